// Round 4
// baseline (1438.778 us; speedup 1.0000x reference)
//
#include <hip/hip_runtime.h>

typedef float f32x4 __attribute__((ext_vector_type(4)));

#define T_STEPS 512
#define BATCH   64
#define NIN     512
#define H       1024
#define BH      (BATCH * H)   // 65536

// ---------------------------------------------------------------------------
// Kernel 1: transpose w_rec [j][h] -> wrecT [h][j]  (4 MB, one-time per call)
// ---------------------------------------------------------------------------
__global__ void transpose1024(const float* __restrict__ in, float* __restrict__ out) {
    __shared__ float tile[32][33];
    const int tx = threadIdx.x, ty = threadIdx.y;
    const int xg = blockIdx.x * 32 + tx;
    const int ybase = blockIdx.y * 32;
#pragma unroll
    for (int r = 0; r < 32; r += 8)
        tile[ty + r][tx] = in[(size_t)(ybase + ty + r) * H + xg];
    __syncthreads();
    const int x2 = blockIdx.y * 32 + tx;
    const int y2base = blockIdx.x * 32;
#pragma unroll
    for (int r = 0; r < 32; r += 8)
        out[(size_t)(y2base + ty + r) * H + x2] = tile[tx][ty + r];
}

// ---------------------------------------------------------------------------
// Kernel 2: cur[m][n] = sum_k x[m][k] * w_in[n][k]  (R7-verbatim, untouched)
// ---------------------------------------------------------------------------
#define BM 128
#define BN 128
#define BK 16
#define LDSS 132

__global__ __launch_bounds__(256) void gemm_xwin(const float* __restrict__ x,
                                                 const float* __restrict__ w,
                                                 float* __restrict__ cur) {
    __shared__ __align__(16) float As[BK][LDSS];
    __shared__ __align__(16) float Bs[BK][LDSS];
    const int tid = threadIdx.x;
    const int tx = tid & 15, ty = tid >> 4;
    const int tx4 = tx * 4, ty4 = ty * 4;
    const int m0 = blockIdx.y * BM;
    const int n0 = blockIdx.x * BN;

    float acc[8][8];
#pragma unroll
    for (int i = 0; i < 8; ++i)
#pragma unroll
        for (int j = 0; j < 8; ++j) acc[i][j] = 0.0f;

    const int ar = tid >> 2;
    const int akc = (tid & 3) * 4;

    for (int k0 = 0; k0 < NIN; k0 += BK) {
        const float4 a0 = *reinterpret_cast<const float4*>(&x[(size_t)(m0 + ar) * NIN + k0 + akc]);
        const float4 a1 = *reinterpret_cast<const float4*>(&x[(size_t)(m0 + ar + 64) * NIN + k0 + akc]);
        const float4 b0 = *reinterpret_cast<const float4*>(&w[(size_t)(n0 + ar) * NIN + k0 + akc]);
        const float4 b1 = *reinterpret_cast<const float4*>(&w[(size_t)(n0 + ar + 64) * NIN + k0 + akc]);
        __syncthreads();
        As[akc + 0][ar] = a0.x; As[akc + 1][ar] = a0.y; As[akc + 2][ar] = a0.z; As[akc + 3][ar] = a0.w;
        As[akc + 0][ar + 64] = a1.x; As[akc + 1][ar + 64] = a1.y; As[akc + 2][ar + 64] = a1.z; As[akc + 3][ar + 64] = a1.w;
        Bs[akc + 0][ar] = b0.x; Bs[akc + 1][ar] = b0.y; Bs[akc + 2][ar] = b0.z; Bs[akc + 3][ar] = b0.w;
        Bs[akc + 0][ar + 64] = b1.x; Bs[akc + 1][ar + 64] = b1.y; Bs[akc + 2][ar + 64] = b1.z; Bs[akc + 3][ar + 64] = b1.w;
        __syncthreads();

#pragma unroll
        for (int kk = 0; kk < BK; ++kk) {
            const float4 av0 = *reinterpret_cast<const float4*>(&As[kk][ty4]);
            const float4 av1 = *reinterpret_cast<const float4*>(&As[kk][ty4 + 64]);
            const float4 bv0 = *reinterpret_cast<const float4*>(&Bs[kk][tx4]);
            const float4 bv1 = *reinterpret_cast<const float4*>(&Bs[kk][tx4 + 64]);
            const float ar_[8] = {av0.x, av0.y, av0.z, av0.w, av1.x, av1.y, av1.z, av1.w};
            const float br_[8] = {bv0.x, bv0.y, bv0.z, bv0.w, bv1.x, bv1.y, bv1.z, bv1.w};
#pragma unroll
            for (int i = 0; i < 8; ++i)
#pragma unroll
                for (int j = 0; j < 8; ++j)
                    acc[i][j] = fmaf(ar_[i], br_[j], acc[i][j]);
        }
    }

#pragma unroll
    for (int gi = 0; gi < 2; ++gi)
#pragma unroll
        for (int ii = 0; ii < 4; ++ii) {
            const int i = gi * 4 + ii;
            const int row = m0 + ty4 + ii + gi * 64;
            float* dst = &cur[(size_t)row * H + n0 + tx4];
            *reinterpret_cast<float4*>(dst)      = make_float4(acc[i][0], acc[i][1], acc[i][2], acc[i][3]);
            *reinterpret_cast<float4*>(dst + 64) = make_float4(acc[i][4], acc[i][5], acc[i][6], acc[i][7]);
        }
}

// ---------------------------------------------------------------------------
// Kernel 3: sequential LSNN scan. R13: one block per batch, **1024 threads x
//   1 neuron each (16 waves/CU)** — latency hiding via TLP instead of the
//   register-heavy ILP that R9/R10/R12 failed on:
//     - gather buffers are SCALAR floats: 3-deep x 16-row pipeline = 48
//       VGPRs (vs 128-192), far below the 128-VGPR/wave cap that 16
//       resident waves require -> no spill, no scheduler serialization
//       pressure.
//     - 16 waves give the CU 16 independent load streams even where a
//       single wave's pipeline partially serializes.
//     - per-wave VALU/LDS work per step drops 4x.
//   Merged flat spike list (cnt[2][16] now), clamped row loads + masked
//   boundary tile (fmaf(0,w,r)=r exact), n carried in a register.
//   Accumulation order (flat list = ascending neuron) and all dynamics ops
//   are bit-identical to R8/R12 (absmax 0.0).
// ---------------------------------------------------------------------------
__global__ __launch_bounds__(1024, 1) void lsnn_scan_kernel(float* __restrict__ io,
                                                            const float* __restrict__ wrecT) {
    const int b = blockIdx.x;
    const int tid = threadIdx.x;          // 0..1023 == neuron/column index
    const int wave = tid >> 6, lane = tid & 63;

    __shared__ __align__(16) int list[2][1088];   // [phase][slot] merged list (+64 pad)
    __shared__ __align__(16) int cnt[2][16];      // [phase][wave] per-wave counts

    float sv = 0.f, si = 0.f, sb = 1.f, sz = 0.f;
    int p = 0;
    int n_carry = 0;

    const float C_MEM = (float)(1e-3 * 100.0);
    const float C_SYN = (float)(1e-3 * 200.0);
    const float C_AD  = (float)(1e-3 * (1.0 / 800.0));
    const float BETA  = 1.8f;

    float* base = io + (size_t)b * H + tid;

    if (lane == 0) cnt[0][wave] = 0;
    asm volatile("s_waitcnt lgkmcnt(0)" ::: "memory");
    __builtin_amdgcn_s_barrier();

    // chunk prefetch buffers: 8 steps of cur (scalar per thread)
    float P0 = base[(size_t)0 * BH];
    float P1 = base[(size_t)1 * BH];
    float P2 = base[(size_t)2 * BH];
    float P3 = base[(size_t)3 * BH];
    float P4 = base[(size_t)4 * BH];
    float P5 = base[(size_t)5 * BH];
    float P6 = base[(size_t)6 * BH];
    float P7 = base[(size_t)7 * BH];

// one row load, clamped: positions >= n read row 0 (safe, cache-hot, masked later)
#define ROWLD(DST, POS, HV)                                                   \
    { const int hc_ = ((POS) < n) ? (HV) : 0;                                 \
      DST = wrecT[(size_t)(unsigned)__builtin_amdgcn_readfirstlane(hc_) * H + tid]; }

// load 16-row tile KT of the flat list (unconditional, clamped)
#define LOAD16C(BUF, KT)                                                      \
  { const int A0_ = (KT) << 4;                                                \
    const int4 q0_ = *reinterpret_cast<const int4*>(lst + A0_);               \
    const int4 q1_ = *reinterpret_cast<const int4*>(lst + A0_ + 4);           \
    const int4 q2_ = *reinterpret_cast<const int4*>(lst + A0_ + 8);           \
    const int4 q3_ = *reinterpret_cast<const int4*>(lst + A0_ + 12);          \
    ROWLD(BUF[0],  A0_ + 0,  q0_.x) ROWLD(BUF[1],  A0_ + 1,  q0_.y)           \
    ROWLD(BUF[2],  A0_ + 2,  q0_.z) ROWLD(BUF[3],  A0_ + 3,  q0_.w)           \
    ROWLD(BUF[4],  A0_ + 4,  q1_.x) ROWLD(BUF[5],  A0_ + 5,  q1_.y)           \
    ROWLD(BUF[6],  A0_ + 6,  q1_.z) ROWLD(BUF[7],  A0_ + 7,  q1_.w)           \
    ROWLD(BUF[8],  A0_ + 8,  q2_.x) ROWLD(BUF[9],  A0_ + 9,  q2_.y)           \
    ROWLD(BUF[10], A0_ + 10, q2_.z) ROWLD(BUF[11], A0_ + 11, q2_.w)           \
    ROWLD(BUF[12], A0_ + 12, q3_.x) ROWLD(BUF[13], A0_ + 13, q3_.y)           \
    ROWLD(BUF[14], A0_ + 14, q3_.z) ROWLD(BUF[15], A0_ + 15, q3_.w)           \
  }

#define ACC16(BUF)                                                            \
  { _Pragma("unroll")                                                         \
    for (int k_ = 0; k_ < 16; ++k_) { r += BUF[k_]; } }

#define ACC16M(BUF, KT)                                                       \
  { const int A0m_ = (KT) << 4;                                               \
    _Pragma("unroll")                                                         \
    for (int k_ = 0; k_ < 16; ++k_) {                                         \
      const float m_ = (A0m_ + k_ < n) ? 1.0f : 0.0f;                         \
      r = fmaf(m_, BUF[k_], r);                                               \
    } }

// full tiles: plain adds (scalar-uniform branch); boundary tile: masked fmaf
#define ACCTILE(BUF, KT)                                                      \
  { if (((((KT) << 4)) + 16) <= n) { ACC16(BUF) } else { ACC16M(BUF, KT) } }

#define SCAN_STEP(T, CREG, PF)                                                \
  {                                                                           \
    const float cc = CREG;                                                    \
    const int n = __builtin_amdgcn_readfirstlane(n_carry);                    \
    const int NT = (n + 15) >> 4;                                             \
    const int* lst = &list[p][0];                                             \
    float wA[16], wB[16], wC[16];                                             \
    float r = 0.f;                                                            \
    /* prologue: issue tile 0 before dynamics/ballot/barriers */              \
    LOAD16C(wA, 0);                                                           \
    /* dynamics (independent of this step's gather) */                        \
    const float vd = sv + C_MEM * (0.0f - sv + si);                           \
    const float id = si - C_SYN * si;                                         \
    const float bd = sb + C_AD * (1.0f - sb);                                 \
    sz = ((vd - bd) > 0.0f) ? 1.0f : 0.0f;                                    \
    sv = (sz > 0.0f) ? 0.0f : vd;                                             \
    sb = (sz > 0.0f) ? (bd + BETA) : bd;                                      \
    base[(size_t)(T) * BH] = sz;                                              \
    const unsigned long long m = __ballot(sz > 0.0f);                         \
    unsigned pos = __builtin_amdgcn_mbcnt_hi((unsigned)(m >> 32),             \
                   __builtin_amdgcn_mbcnt_lo((unsigned)m, 0u));               \
    if (lane == 0) cnt[p ^ 1][wave] = __popcll(m);                            \
    asm volatile("s_waitcnt lgkmcnt(0)" ::: "memory");                        \
    __builtin_amdgcn_s_barrier();                                             \
    /* cross-wave prefix over 16 counts -> merged list; carry next n */       \
    const int4 c0 = *reinterpret_cast<const int4*>(&cnt[p ^ 1][0]);           \
    const int4 c1 = *reinterpret_cast<const int4*>(&cnt[p ^ 1][4]);           \
    const int4 c2 = *reinterpret_cast<const int4*>(&cnt[p ^ 1][8]);           \
    const int4 c3 = *reinterpret_cast<const int4*>(&cnt[p ^ 1][12]);          \
    n_carry = (c0.x + c0.y + c0.z + c0.w) + (c1.x + c1.y + c1.z + c1.w) +     \
              (c2.x + c2.y + c2.z + c2.w) + (c3.x + c3.y + c3.z + c3.w);      \
    int woff = 0;                                                             \
    woff += (wave > 0)  ? c0.x : 0;  woff += (wave > 1)  ? c0.y : 0;          \
    woff += (wave > 2)  ? c0.z : 0;  woff += (wave > 3)  ? c0.w : 0;          \
    woff += (wave > 4)  ? c1.x : 0;  woff += (wave > 5)  ? c1.y : 0;          \
    woff += (wave > 6)  ? c1.z : 0;  woff += (wave > 7)  ? c1.w : 0;          \
    woff += (wave > 8)  ? c2.x : 0;  woff += (wave > 9)  ? c2.y : 0;          \
    woff += (wave > 10) ? c2.z : 0;  woff += (wave > 11) ? c2.w : 0;          \
    woff += (wave > 12) ? c3.x : 0;  woff += (wave > 13) ? c3.y : 0;          \
    woff += (wave > 14) ? c3.z : 0;                                           \
    if (sz > 0.0f) list[p ^ 1][woff + (int)pos] = tid;                        \
    asm volatile("s_waitcnt lgkmcnt(0)" ::: "memory");                        \
    __builtin_amdgcn_s_barrier();                                             \
    /* 3-deep x 16-row pipelined gather (scalar buffers, branch-free body) */ \
    if (n > 0) {                                                              \
      LOAD16C(wB, 1);                                                         \
      LOAD16C(wC, 2);                                                         \
      int kt = 0;                                                             \
      for (; kt + 3 < NT; kt += 3) {                                          \
        ACCTILE(wA, kt);     LOAD16C(wA, kt + 3);                             \
        ACCTILE(wB, kt + 1); LOAD16C(wB, kt + 4);                             \
        ACCTILE(wC, kt + 2); LOAD16C(wC, kt + 5);                             \
      }                                                                       \
      ACCTILE(wA, kt);                                                        \
      if (kt + 1 < NT) ACCTILE(wB, kt + 1);                                   \
      if (kt + 2 < NT) ACCTILE(wC, kt + 2);                                   \
    }                                                                         \
    if (PF) {                                                                 \
      if ((T) + 1 < T_STEPS) {                                                \
        const float* pb = base + (size_t)((T) + 1) * BH;                      \
        P0 = pb[(size_t)0 * BH];                                              \
        P1 = pb[(size_t)1 * BH];                                              \
        P2 = pb[(size_t)2 * BH];                                              \
        P3 = pb[(size_t)3 * BH];                                              \
        P4 = pb[(size_t)4 * BH];                                              \
        P5 = pb[(size_t)5 * BH];                                              \
        P6 = pb[(size_t)6 * BH];                                              \
        P7 = pb[(size_t)7 * BH];                                              \
      }                                                                       \
    }                                                                         \
    si = (id + cc) + r;                                                       \
    p ^= 1;                                                                   \
  }

    for (int t = 0; t < T_STEPS; t += 8) {
        SCAN_STEP(t,     P0, 0);
        SCAN_STEP(t + 1, P1, 0);
        SCAN_STEP(t + 2, P2, 0);
        SCAN_STEP(t + 3, P3, 0);
        SCAN_STEP(t + 4, P4, 0);
        SCAN_STEP(t + 5, P5, 0);
        SCAN_STEP(t + 6, P6, 0);
        SCAN_STEP(t + 7, P7, 1);
    }
#undef SCAN_STEP
#undef ACCTILE
#undef ACC16M
#undef ACC16
#undef LOAD16C
#undef ROWLD

    float* fo = io + (size_t)T_STEPS * BH + (size_t)b * H + tid;
    fo[0]          = sz;
    fo[BH]         = sv;
    fo[2 * BH]     = si;
    fo[3 * BH]     = sb;
}

// ---------------------------------------------------------------------------
extern "C" void kernel_launch(void* const* d_in, const int* in_sizes, int n_in,
                              void* d_out, int out_size, void* d_ws, size_t ws_size,
                              hipStream_t stream) {
    const float* x     = (const float*)d_in[0];
    const float* w_in  = (const float*)d_in[1];
    const float* w_rec = (const float*)d_in[2];
    float* out   = (float*)d_out;
    float* wrecT = (float*)d_ws;

    transpose1024<<<dim3(H / 32, H / 32), dim3(32, 8), 0, stream>>>(w_rec, wrecT);
    gemm_xwin<<<dim3(H / BN, (T_STEPS * BATCH) / BM), 256, 0, stream>>>(x, w_in, out);
    lsnn_scan_kernel<<<BATCH, 1024, 0, stream>>>(out, wrecT);
}

// Round 5
// 880.249 us; speedup vs baseline: 1.6345x; 1.6345x over previous
//
#include <hip/hip_runtime.h>

typedef float f32x4 __attribute__((ext_vector_type(4)));

#define T_STEPS 512
#define BATCH   64
#define NIN     512
#define H       1024
#define BH      (BATCH * H)   // 65536
#define SENTU   0x7F7F7F7Fu  // sentinel bit pattern (3.39e38f; GEMM can't produce it)

#define BM 128
#define BN 128
#define BK 16
#define LDSS 132
#define SCAN_BLOCKS 64
#define GEMM_BLOCKS ((T_STEPS * BATCH / BM) * (H / BN))   // 256*8 = 2048

// device-coherent (agent-scope) scalar access: bypasses per-XCD caches so
// producer (GEMM blocks, any XCD) and consumer (scan blocks, any XCD) meet
// at the device coherence point. RELAXED: no fences, no L2 invalidation
// (critical: keeps wrecT L2-resident for the scan's gather).
__device__ __forceinline__ float ld_agent(const float* p) {
    return __hip_atomic_load(p, __ATOMIC_RELAXED, __HIP_MEMORY_SCOPE_AGENT);
}
__device__ __forceinline__ void st_agent(float* p, float v) {
    __hip_atomic_store(p, v, __ATOMIC_RELAXED, __HIP_MEMORY_SCOPE_AGENT);
}

// ---------------------------------------------------------------------------
// Kernel 1: transpose w_rec [j][h] -> wrecT [h][j]  (4 MB, one-time per call)
// Runs before the fused kernel (stream order) -> wrecT device-visible.
// ---------------------------------------------------------------------------
__global__ void transpose1024(const float* __restrict__ in, float* __restrict__ out) {
    __shared__ float tile[32][33];
    const int tx = threadIdx.x, ty = threadIdx.y;
    const int xg = blockIdx.x * 32 + tx;
    const int ybase = blockIdx.y * 32;
#pragma unroll
    for (int r = 0; r < 32; r += 8)
        tile[ty + r][tx] = in[(size_t)(ybase + ty + r) * H + xg];
    __syncthreads();
    const int x2 = blockIdx.y * 32 + tx;
    const int y2base = blockIdx.x * 32;
#pragma unroll
    for (int r = 0; r < 32; r += 8)
        out[(size_t)(y2base + ty + r) * H + x2] = tile[tx][ty + r];
}

// ---------------------------------------------------------------------------
// Fused kernel. Blocks [0,64): R8-verbatim LSNN scan (one block per batch,
// 256 thr x 4 neurons, per-wave spike lists, 8-step chunked cur prefetch).
// Blocks [64, 64+2048): R7-verbatim fp32 GEMM cur[m][n] = x @ w_in^T, with
// the epilogue stores switched to agent-scope scalar stores. y-major block
// order -> m-tiles (i.e. timesteps, m = t*64+b) complete in roughly
// ascending t, feeding the scan as it runs.
// Synchronization: cur region pre-filled with 0x7F sentinel bytes by
// hipMemsetAsync; scan spins (bounded, s_sleep) on its 8-step prefetch
// until all values are non-sentinel. Values are written once, so a
// non-sentinel read is final -> no fences needed.
// ---------------------------------------------------------------------------
__global__ void fused_gemm_scan(const float* __restrict__ x,
                                const float* __restrict__ w,
                                float* __restrict__ io,
                                const float* __restrict__ wrecT) {
    // shared memory union: GEMM needs 2*BK*LDSS floats (16896 B), scan needs
    // list[2][4][256] + cnt[2][4] ints (8224 B).
    __shared__ __align__(16) char smem[2 * BK * LDSS * sizeof(float)];

    if (blockIdx.x >= SCAN_BLOCKS) {
        // ------------------------- GEMM path (R7-verbatim math) -----------
        float* cur = io;
        const int g = blockIdx.x - SCAN_BLOCKS;
        const int m0 = (g >> 3) * BM;        // y-major: ascending timestep
        const int n0 = (g & 7) * BN;

        float (*As)[LDSS] = reinterpret_cast<float (*)[LDSS]>(smem);
        float (*Bs)[LDSS] = reinterpret_cast<float (*)[LDSS]>(smem + BK * LDSS * sizeof(float));

        const int tid = threadIdx.x;
        const int tx = tid & 15, ty = tid >> 4;
        const int tx4 = tx * 4, ty4 = ty * 4;

        float acc[8][8];
#pragma unroll
        for (int i = 0; i < 8; ++i)
#pragma unroll
            for (int j = 0; j < 8; ++j) acc[i][j] = 0.0f;

        const int ar = tid >> 2;
        const int akc = (tid & 3) * 4;

        for (int k0 = 0; k0 < NIN; k0 += BK) {
            const float4 a0 = *reinterpret_cast<const float4*>(&x[(size_t)(m0 + ar) * NIN + k0 + akc]);
            const float4 a1 = *reinterpret_cast<const float4*>(&x[(size_t)(m0 + ar + 64) * NIN + k0 + akc]);
            const float4 b0 = *reinterpret_cast<const float4*>(&w[(size_t)(n0 + ar) * NIN + k0 + akc]);
            const float4 b1 = *reinterpret_cast<const float4*>(&w[(size_t)(n0 + ar + 64) * NIN + k0 + akc]);
            __syncthreads();
            As[akc + 0][ar] = a0.x; As[akc + 1][ar] = a0.y; As[akc + 2][ar] = a0.z; As[akc + 3][ar] = a0.w;
            As[akc + 0][ar + 64] = a1.x; As[akc + 1][ar + 64] = a1.y; As[akc + 2][ar + 64] = a1.z; As[akc + 3][ar + 64] = a1.w;
            Bs[akc + 0][ar] = b0.x; Bs[akc + 1][ar] = b0.y; Bs[akc + 2][ar] = b0.z; Bs[akc + 3][ar] = b0.w;
            Bs[akc + 0][ar + 64] = b1.x; Bs[akc + 1][ar + 64] = b1.y; Bs[akc + 2][ar + 64] = b1.z; Bs[akc + 3][ar + 64] = b1.w;
            __syncthreads();

#pragma unroll
            for (int kk = 0; kk < BK; ++kk) {
                const float4 av0 = *reinterpret_cast<const float4*>(&As[kk][ty4]);
                const float4 av1 = *reinterpret_cast<const float4*>(&As[kk][ty4 + 64]);
                const float4 bv0 = *reinterpret_cast<const float4*>(&Bs[kk][tx4]);
                const float4 bv1 = *reinterpret_cast<const float4*>(&Bs[kk][tx4 + 64]);
                const float ar_[8] = {av0.x, av0.y, av0.z, av0.w, av1.x, av1.y, av1.z, av1.w};
                const float br_[8] = {bv0.x, bv0.y, bv0.z, bv0.w, bv1.x, bv1.y, bv1.z, bv1.w};
#pragma unroll
                for (int i = 0; i < 8; ++i)
#pragma unroll
                    for (int j = 0; j < 8; ++j)
                        acc[i][j] = fmaf(ar_[i], br_[j], acc[i][j]);
            }
        }

        // epilogue: agent-scope scalar stores (device-coherent, bit-identical values)
#pragma unroll
        for (int gi = 0; gi < 2; ++gi)
#pragma unroll
            for (int ii = 0; ii < 4; ++ii) {
                const int i = gi * 4 + ii;
                const int row = m0 + ty4 + ii + gi * 64;
                float* dst = &cur[(size_t)row * H + n0 + tx4];
                st_agent(dst + 0,  acc[i][0]); st_agent(dst + 1,  acc[i][1]);
                st_agent(dst + 2,  acc[i][2]); st_agent(dst + 3,  acc[i][3]);
                st_agent(dst + 64, acc[i][4]); st_agent(dst + 65, acc[i][5]);
                st_agent(dst + 66, acc[i][6]); st_agent(dst + 67, acc[i][7]);
            }
        return;
    }

    // ----------------------------- scan path (R8-verbatim) ----------------
    const int b = blockIdx.x;
    const int tid = threadIdx.x;
    const int wave = tid >> 6, lane = tid & 63;
    const int j0 = tid * 4;

    int (*list)[4][256] = reinterpret_cast<int (*)[4][256]>(smem);          // 8192 B
    int (*cnt)[4]       = reinterpret_cast<int (*)[4]>(smem + 8192);        // 32 B

    float sv0 = 0.f, sv1 = 0.f, sv2 = 0.f, sv3 = 0.f;
    float si0 = 0.f, si1 = 0.f, si2 = 0.f, si3 = 0.f;
    float sb0 = 1.f, sb1 = 1.f, sb2 = 1.f, sb3 = 1.f;
    float sz0 = 0.f, sz1 = 0.f, sz2 = 0.f, sz3 = 0.f;
    int p = 0;

    const float C_MEM = (float)(1e-3 * 100.0);
    const float C_SYN = (float)(1e-3 * 200.0);
    const float C_AD  = (float)(1e-3 * (1.0 / 800.0));
    const float BETA  = 1.8f;

    float* base = io + (size_t)b * H + j0;

    if (lane == 0) cnt[0][wave] = 0;
    asm volatile("s_waitcnt lgkmcnt(0)" ::: "memory");
    __builtin_amdgcn_s_barrier();

    f32x4 P0, P1, P2, P3, P4, P5, P6, P7;

// one prefetch register: 4 agent-scope scalar loads + sentinel check
#define LDP(REG, KK)                                                          \
      REG.x = ld_agent(pb_ + (size_t)(KK) * BH + 0);                          \
      REG.y = ld_agent(pb_ + (size_t)(KK) * BH + 1);                          \
      REG.z = ld_agent(pb_ + (size_t)(KK) * BH + 2);                          \
      REG.w = ld_agent(pb_ + (size_t)(KK) * BH + 3);                          \
      bad_ |= (unsigned)(__float_as_uint(REG.x) == SENTU);                    \
      bad_ |= (unsigned)(__float_as_uint(REG.y) == SENTU);                    \
      bad_ |= (unsigned)(__float_as_uint(REG.z) == SENTU);                    \
      bad_ |= (unsigned)(__float_as_uint(REG.w) == SENTU);

// spin (bounded) until the next 8 steps of cur are all produced by the GEMM
#define LOADP8_SPIN(PBASE)                                                    \
  { const float* pb_ = (PBASE);                                               \
    for (int tries_ = 0; tries_ < (1 << 14); ++tries_) {                      \
      unsigned bad_ = 0u;                                                     \
      LDP(P0, 0) LDP(P1, 1) LDP(P2, 2) LDP(P3, 3)                             \
      LDP(P4, 4) LDP(P5, 5) LDP(P6, 6) LDP(P7, 7)                             \
      if (__ballot(bad_ != 0u) == 0ull) break;                                \
      __builtin_amdgcn_s_sleep(8);                                            \
    } }

    // chunk prefetch: 8 steps of cur (spin until GEMM has produced them)
    LOADP8_SPIN(base);

#define SCAN_STEP(T, CREG, PF)                                                \
  {                                                                           \
    const float cc0 = CREG.x, cc1 = CREG.y, cc2 = CREG.z, cc3 = CREG.w;       \
    const int4 cn = *reinterpret_cast<const int4*>(&cnt[p][0]);               \
    float r0 = 0.f, r1 = 0.f, r2 = 0.f, r3 = 0.f;                             \
    _Pragma("unroll")                                                         \
    for (int w = 0; w < 4; ++w) {                                             \
      const int nw = (w == 0) ? cn.x : (w == 1) ? cn.y : (w == 2) ? cn.z : cn.w; \
      const int* lst = &list[p][w][0];                                        \
      int a = 0;                                                              \
      for (; a + 8 <= nw; a += 8) {                                           \
        const int h0 = lst[a],     h1 = lst[a + 1];                           \
        const int h2 = lst[a + 2], h3 = lst[a + 3];                           \
        const int h4 = lst[a + 4], h5 = lst[a + 5];                           \
        const int h6 = lst[a + 6], h7 = lst[a + 7];                           \
        const f32x4 wa = *(const f32x4*)(wrecT + (size_t)h0 * H + j0);        \
        const f32x4 wb = *(const f32x4*)(wrecT + (size_t)h1 * H + j0);        \
        const f32x4 wc = *(const f32x4*)(wrecT + (size_t)h2 * H + j0);        \
        const f32x4 wd = *(const f32x4*)(wrecT + (size_t)h3 * H + j0);        \
        const f32x4 we = *(const f32x4*)(wrecT + (size_t)h4 * H + j0);        \
        const f32x4 wf = *(const f32x4*)(wrecT + (size_t)h5 * H + j0);        \
        const f32x4 wg = *(const f32x4*)(wrecT + (size_t)h6 * H + j0);        \
        const f32x4 wh = *(const f32x4*)(wrecT + (size_t)h7 * H + j0);        \
        r0 += wa.x; r1 += wa.y; r2 += wa.z; r3 += wa.w;                       \
        r0 += wb.x; r1 += wb.y; r2 += wb.z; r3 += wb.w;                       \
        r0 += wc.x; r1 += wc.y; r2 += wc.z; r3 += wc.w;                       \
        r0 += wd.x; r1 += wd.y; r2 += wd.z; r3 += wd.w;                       \
        r0 += we.x; r1 += we.y; r2 += we.z; r3 += we.w;                       \
        r0 += wf.x; r1 += wf.y; r2 += wf.z; r3 += wf.w;                       \
        r0 += wg.x; r1 += wg.y; r2 += wg.z; r3 += wg.w;                       \
        r0 += wh.x; r1 += wh.y; r2 += wh.z; r3 += wh.w;                       \
      }                                                                       \
      for (; a < nw; ++a) {                                                   \
        const int h = lst[a];                                                 \
        const f32x4 w4 = *(const f32x4*)(wrecT + (size_t)h * H + j0);         \
        r0 += w4.x; r1 += w4.y; r2 += w4.z; r3 += w4.w;                       \
      }                                                                       \
    }                                                                         \
    const float vd0 = sv0 + C_MEM * (0.0f - sv0 + si0);                       \
    const float vd1 = sv1 + C_MEM * (0.0f - sv1 + si1);                       \
    const float vd2 = sv2 + C_MEM * (0.0f - sv2 + si2);                       \
    const float vd3 = sv3 + C_MEM * (0.0f - sv3 + si3);                       \
    const float id0 = si0 - C_SYN * si0;                                      \
    const float id1 = si1 - C_SYN * si1;                                      \
    const float id2 = si2 - C_SYN * si2;                                      \
    const float id3 = si3 - C_SYN * si3;                                      \
    const float bd0 = sb0 + C_AD * (1.0f - sb0);                              \
    const float bd1 = sb1 + C_AD * (1.0f - sb1);                              \
    const float bd2 = sb2 + C_AD * (1.0f - sb2);                              \
    const float bd3 = sb3 + C_AD * (1.0f - sb3);                              \
    sz0 = ((vd0 - bd0) > 0.0f) ? 1.0f : 0.0f;                                 \
    sz1 = ((vd1 - bd1) > 0.0f) ? 1.0f : 0.0f;                                 \
    sz2 = ((vd2 - bd2) > 0.0f) ? 1.0f : 0.0f;                                 \
    sz3 = ((vd3 - bd3) > 0.0f) ? 1.0f : 0.0f;                                 \
    sv0 = (sz0 > 0.0f) ? 0.0f : vd0;                                          \
    sv1 = (sz1 > 0.0f) ? 0.0f : vd1;                                          \
    sv2 = (sz2 > 0.0f) ? 0.0f : vd2;                                          \
    sv3 = (sz3 > 0.0f) ? 0.0f : vd3;                                          \
    sb0 = (sz0 > 0.0f) ? (bd0 + BETA) : bd0;                                  \
    sb1 = (sz1 > 0.0f) ? (bd1 + BETA) : bd1;                                  \
    sb2 = (sz2 > 0.0f) ? (bd2 + BETA) : bd2;                                  \
    sb3 = (sz3 > 0.0f) ? (bd3 + BETA) : bd3;                                  \
    si0 = (id0 + cc0) + r0;                                                   \
    si1 = (id1 + cc1) + r1;                                                   \
    si2 = (id2 + cc2) + r2;                                                   \
    si3 = (id3 + cc3) + r3;                                                   \
    if (PF) {                                                                 \
      /* next chunk's cur loads (spin until produced by GEMM) */              \
      if ((T) + 1 < T_STEPS) {                                                \
        LOADP8_SPIN(base + (size_t)((T) + 1) * BH);                           \
      }                                                                       \
    }                                                                         \
    *reinterpret_cast<f32x4*>(base + (size_t)(T) * BH) =                      \
        (f32x4){sz0, sz1, sz2, sz3};                                          \
    const unsigned long long m0 = __ballot(sz0 > 0.0f);                       \
    const unsigned long long m1 = __ballot(sz1 > 0.0f);                       \
    const unsigned long long m2 = __ballot(sz2 > 0.0f);                       \
    const unsigned long long m3 = __ballot(sz3 > 0.0f);                       \
    unsigned pos = __builtin_amdgcn_mbcnt_hi((unsigned)(m0 >> 32),            \
                   __builtin_amdgcn_mbcnt_lo((unsigned)m0, 0u));              \
    pos = __builtin_amdgcn_mbcnt_hi((unsigned)(m1 >> 32),                     \
          __builtin_amdgcn_mbcnt_lo((unsigned)m1, pos));                      \
    pos = __builtin_amdgcn_mbcnt_hi((unsigned)(m2 >> 32),                     \
          __builtin_amdgcn_mbcnt_lo((unsigned)m2, pos));                      \
    pos = __builtin_amdgcn_mbcnt_hi((unsigned)(m3 >> 32),                     \
          __builtin_amdgcn_mbcnt_lo((unsigned)m3, pos));                      \
    int* dst = &list[p ^ 1][wave][0];                                         \
    if (sz0 > 0.0f) dst[pos++] = j0 + 0;                                      \
    if (sz1 > 0.0f) dst[pos++] = j0 + 1;                                      \
    if (sz2 > 0.0f) dst[pos++] = j0 + 2;                                      \
    if (sz3 > 0.0f) dst[pos++] = j0 + 3;                                      \
    if (lane == 0)                                                            \
      cnt[p ^ 1][wave] = __popcll(m0) + __popcll(m1) + __popcll(m2) + __popcll(m3); \
    asm volatile("s_waitcnt lgkmcnt(0)" ::: "memory");                        \
    __builtin_amdgcn_s_barrier();                                             \
    p ^= 1;                                                                   \
  }

    for (int t = 0; t < T_STEPS; t += 8) {
        SCAN_STEP(t,     P0, 0);
        SCAN_STEP(t + 1, P1, 0);
        SCAN_STEP(t + 2, P2, 0);
        SCAN_STEP(t + 3, P3, 0);
        SCAN_STEP(t + 4, P4, 0);
        SCAN_STEP(t + 5, P5, 0);
        SCAN_STEP(t + 6, P6, 0);
        SCAN_STEP(t + 7, P7, 1);
    }
#undef SCAN_STEP
#undef LOADP8_SPIN
#undef LDP

    float* fo = io + (size_t)T_STEPS * BH + (size_t)b * H + j0;
    *reinterpret_cast<float4*>(fo)          = make_float4(sz0, sz1, sz2, sz3);
    *reinterpret_cast<float4*>(fo + BH)     = make_float4(sv0, sv1, sv2, sv3);
    *reinterpret_cast<float4*>(fo + 2 * BH) = make_float4(si0, si1, si2, si3);
    *reinterpret_cast<float4*>(fo + 3 * BH) = make_float4(sb0, sb1, sb2, sb3);
}

// ---------------------------------------------------------------------------
extern "C" void kernel_launch(void* const* d_in, const int* in_sizes, int n_in,
                              void* d_out, int out_size, void* d_ws, size_t ws_size,
                              hipStream_t stream) {
    const float* x     = (const float*)d_in[0];
    const float* w_in  = (const float*)d_in[1];
    const float* w_rec = (const float*)d_in[2];
    float* out   = (float*)d_out;
    float* wrecT = (float*)d_ws;

    // arm the sentinel over the cur/z region (first T*BH floats of io)
    hipMemsetAsync(out, 0x7F, (size_t)T_STEPS * BH * sizeof(float), stream);
    transpose1024<<<dim3(H / 32, H / 32), dim3(32, 8), 0, stream>>>(w_rec, wrecT);
    fused_gemm_scan<<<dim3(SCAN_BLOCKS + GEMM_BLOCKS), 256, 0, stream>>>(x, w_in, out, wrecT);
}

// Round 6
// 757.809 us; speedup vs baseline: 1.8986x; 1.1616x over previous
//
#include <hip/hip_runtime.h>

typedef float f32x4 __attribute__((ext_vector_type(4)));

#define T_STEPS 512
#define BATCH   64
#define NIN     512
#define H       1024
#define BH      (BATCH * H)   // 65536
#define SENTU   0x7F7F7F7Fu  // sentinel bit pattern (3.39e38f; GEMM can't produce it)

#define BM 128
#define BN 128
#define BK 16
#define LDSS 132
#define NUM_GEMM 2048
// grid: 342 groups of 8 slots; slots {0,1} of first 32 groups = 64 scan
// blocks (XCDs 0,1); slots {2..7} = 2052 GEMM slots (2048 used, XCDs 2-7).
#define GRID_BLOCKS (342 * 8)

// device-coherent (agent-scope) scalar access: bypasses per-XCD caches so
// producer (GEMM blocks, XCD 2-7) and consumer (scan blocks, XCD 0-1) meet
// at the device coherence point. RELAXED: no fences, no cache invalidation
// (critical: keeps wrecT L2-resident on the scan XCDs).
__device__ __forceinline__ float ld_agent(const float* p) {
    return __hip_atomic_load(p, __ATOMIC_RELAXED, __HIP_MEMORY_SCOPE_AGENT);
}
__device__ __forceinline__ void st_agent(float* p, float v) {
    __hip_atomic_store(p, v, __ATOMIC_RELAXED, __HIP_MEMORY_SCOPE_AGENT);
}

// ---------------------------------------------------------------------------
// Kernel 1: transpose w_rec [j][h] -> wrecT [h][j]  (4 MB, one-time per call)
// ---------------------------------------------------------------------------
__global__ void transpose1024(const float* __restrict__ in, float* __restrict__ out) {
    __shared__ float tile[32][33];
    const int tx = threadIdx.x, ty = threadIdx.y;
    const int xg = blockIdx.x * 32 + tx;
    const int ybase = blockIdx.y * 32;
#pragma unroll
    for (int r = 0; r < 32; r += 8)
        tile[ty + r][tx] = in[(size_t)(ybase + ty + r) * H + xg];
    __syncthreads();
    const int x2 = blockIdx.y * 32 + tx;
    const int y2base = blockIdx.x * 32;
#pragma unroll
    for (int r = 0; r < 32; r += 8)
        out[(size_t)(y2base + ty + r) * H + x2] = tile[tx][ty + r];
}

// ---------------------------------------------------------------------------
// Fused kernel with XCD partition (R15).
//   slot = blockIdx.x % 8 (== XCD on MI355X, round-robin dispatch):
//     slot 0,1 & blockIdx.x < 256  -> 64 scan blocks, XCDs {0,1}: 1 block/CU,
//                                     wrecT stays L2-resident (no GEMM here).
//     slot 2..7                    -> 2048 GEMM blocks, XCDs {2..7} (192 CUs).
//     everything else              -> no-op.
//   Mapping is a PERF-only assumption: correctness (sentinel spin sync)
//   holds under any placement. All FP math verbatim R8/R14 (absmax 0.0).
// ---------------------------------------------------------------------------
__global__ void fused_gemm_scan(const float* __restrict__ x,
                                const float* __restrict__ w,
                                float* __restrict__ io,
                                const float* __restrict__ wrecT) {
    // shared memory union: GEMM needs 2*BK*LDSS floats (16896 B), scan needs
    // list[2][4][256] + cnt[2][4] ints (8224 B).
    __shared__ __align__(16) char smem[2 * BK * LDSS * sizeof(float)];

    const int slot = blockIdx.x & 7;
    if (slot >= 2) {
        // ------------------------- GEMM path (R7-verbatim math) -----------
        const int g = (blockIdx.x >> 3) * 6 + (slot - 2);
        if (g >= NUM_GEMM) return;
        float* cur = io;
        const int m0 = (g >> 3) * BM;        // y-major: ascending timestep
        const int n0 = (g & 7) * BN;

        float (*As)[LDSS] = reinterpret_cast<float (*)[LDSS]>(smem);
        float (*Bs)[LDSS] = reinterpret_cast<float (*)[LDSS]>(smem + BK * LDSS * sizeof(float));

        const int tid = threadIdx.x;
        const int tx = tid & 15, ty = tid >> 4;
        const int tx4 = tx * 4, ty4 = ty * 4;

        float acc[8][8];
#pragma unroll
        for (int i = 0; i < 8; ++i)
#pragma unroll
            for (int j = 0; j < 8; ++j) acc[i][j] = 0.0f;

        const int ar = tid >> 2;
        const int akc = (tid & 3) * 4;

        for (int k0 = 0; k0 < NIN; k0 += BK) {
            const float4 a0 = *reinterpret_cast<const float4*>(&x[(size_t)(m0 + ar) * NIN + k0 + akc]);
            const float4 a1 = *reinterpret_cast<const float4*>(&x[(size_t)(m0 + ar + 64) * NIN + k0 + akc]);
            const float4 b0 = *reinterpret_cast<const float4*>(&w[(size_t)(n0 + ar) * NIN + k0 + akc]);
            const float4 b1 = *reinterpret_cast<const float4*>(&w[(size_t)(n0 + ar + 64) * NIN + k0 + akc]);
            __syncthreads();
            As[akc + 0][ar] = a0.x; As[akc + 1][ar] = a0.y; As[akc + 2][ar] = a0.z; As[akc + 3][ar] = a0.w;
            As[akc + 0][ar + 64] = a1.x; As[akc + 1][ar + 64] = a1.y; As[akc + 2][ar + 64] = a1.z; As[akc + 3][ar + 64] = a1.w;
            Bs[akc + 0][ar] = b0.x; Bs[akc + 1][ar] = b0.y; Bs[akc + 2][ar] = b0.z; Bs[akc + 3][ar] = b0.w;
            Bs[akc + 0][ar + 64] = b1.x; Bs[akc + 1][ar + 64] = b1.y; Bs[akc + 2][ar + 64] = b1.z; Bs[akc + 3][ar + 64] = b1.w;
            __syncthreads();

#pragma unroll
            for (int kk = 0; kk < BK; ++kk) {
                const float4 av0 = *reinterpret_cast<const float4*>(&As[kk][ty4]);
                const float4 av1 = *reinterpret_cast<const float4*>(&As[kk][ty4 + 64]);
                const float4 bv0 = *reinterpret_cast<const float4*>(&Bs[kk][tx4]);
                const float4 bv1 = *reinterpret_cast<const float4*>(&Bs[kk][tx4 + 64]);
                const float ar_[8] = {av0.x, av0.y, av0.z, av0.w, av1.x, av1.y, av1.z, av1.w};
                const float br_[8] = {bv0.x, bv0.y, bv0.z, bv0.w, bv1.x, bv1.y, bv1.z, bv1.w};
#pragma unroll
                for (int i = 0; i < 8; ++i)
#pragma unroll
                    for (int j = 0; j < 8; ++j)
                        acc[i][j] = fmaf(ar_[i], br_[j], acc[i][j]);
            }
        }

        // epilogue: agent-scope scalar stores (device-coherent, bit-identical values)
#pragma unroll
        for (int gi = 0; gi < 2; ++gi)
#pragma unroll
            for (int ii = 0; ii < 4; ++ii) {
                const int i = gi * 4 + ii;
                const int row = m0 + ty4 + ii + gi * 64;
                float* dst = &cur[(size_t)row * H + n0 + tx4];
                st_agent(dst + 0,  acc[i][0]); st_agent(dst + 1,  acc[i][1]);
                st_agent(dst + 2,  acc[i][2]); st_agent(dst + 3,  acc[i][3]);
                st_agent(dst + 64, acc[i][4]); st_agent(dst + 65, acc[i][5]);
                st_agent(dst + 66, acc[i][6]); st_agent(dst + 67, acc[i][7]);
            }
        return;
    }

    // ----------------------------- scan path (R8-verbatim) ----------------
    if (blockIdx.x >= 256) return;                 // only first 32 groups
    const int b = (blockIdx.x >> 3) * 2 + slot;    // 0..63
    const int tid = threadIdx.x;
    const int wave = tid >> 6, lane = tid & 63;
    const int j0 = tid * 4;

    int (*list)[4][256] = reinterpret_cast<int (*)[4][256]>(smem);          // 8192 B
    int (*cnt)[4]       = reinterpret_cast<int (*)[4]>(smem + 8192);        // 32 B

    float sv0 = 0.f, sv1 = 0.f, sv2 = 0.f, sv3 = 0.f;
    float si0 = 0.f, si1 = 0.f, si2 = 0.f, si3 = 0.f;
    float sb0 = 1.f, sb1 = 1.f, sb2 = 1.f, sb3 = 1.f;
    float sz0 = 0.f, sz1 = 0.f, sz2 = 0.f, sz3 = 0.f;
    int p = 0;

    const float C_MEM = (float)(1e-3 * 100.0);
    const float C_SYN = (float)(1e-3 * 200.0);
    const float C_AD  = (float)(1e-3 * (1.0 / 800.0));
    const float BETA  = 1.8f;

    float* base = io + (size_t)b * H + j0;

    if (lane == 0) cnt[0][wave] = 0;
    asm volatile("s_waitcnt lgkmcnt(0)" ::: "memory");
    __builtin_amdgcn_s_barrier();

    f32x4 P0, P1, P2, P3, P4, P5, P6, P7;

// one prefetch register: 4 agent-scope scalar loads + sentinel check
#define LDP(REG, KK)                                                          \
      REG.x = ld_agent(pb_ + (size_t)(KK) * BH + 0);                          \
      REG.y = ld_agent(pb_ + (size_t)(KK) * BH + 1);                          \
      REG.z = ld_agent(pb_ + (size_t)(KK) * BH + 2);                          \
      REG.w = ld_agent(pb_ + (size_t)(KK) * BH + 3);                          \
      bad_ |= (unsigned)(__float_as_uint(REG.x) == SENTU);                    \
      bad_ |= (unsigned)(__float_as_uint(REG.y) == SENTU);                    \
      bad_ |= (unsigned)(__float_as_uint(REG.z) == SENTU);                    \
      bad_ |= (unsigned)(__float_as_uint(REG.w) == SENTU);

// spin (bounded) until the next 8 steps of cur are all produced by the GEMM
#define LOADP8_SPIN(PBASE)                                                    \
  { const float* pb_ = (PBASE);                                               \
    for (int tries_ = 0; tries_ < (1 << 14); ++tries_) {                      \
      unsigned bad_ = 0u;                                                     \
      LDP(P0, 0) LDP(P1, 1) LDP(P2, 2) LDP(P3, 3)                             \
      LDP(P4, 4) LDP(P5, 5) LDP(P6, 6) LDP(P7, 7)                             \
      if (__ballot(bad_ != 0u) == 0ull) break;                                \
      __builtin_amdgcn_s_sleep(8);                                            \
    } }

    // chunk prefetch: 8 steps of cur (spin until GEMM has produced them)
    LOADP8_SPIN(base);

#define SCAN_STEP(T, CREG, PF)                                                \
  {                                                                           \
    const float cc0 = CREG.x, cc1 = CREG.y, cc2 = CREG.z, cc3 = CREG.w;       \
    const int4 cn = *reinterpret_cast<const int4*>(&cnt[p][0]);               \
    float r0 = 0.f, r1 = 0.f, r2 = 0.f, r3 = 0.f;                             \
    _Pragma("unroll")                                                         \
    for (int w = 0; w < 4; ++w) {                                             \
      const int nw = (w == 0) ? cn.x : (w == 1) ? cn.y : (w == 2) ? cn.z : cn.w; \
      const int* lst = &list[p][w][0];                                        \
      int a = 0;                                                              \
      for (; a + 8 <= nw; a += 8) {                                           \
        const int h0 = lst[a],     h1 = lst[a + 1];                           \
        const int h2 = lst[a + 2], h3 = lst[a + 3];                           \
        const int h4 = lst[a + 4], h5 = lst[a + 5];                           \
        const int h6 = lst[a + 6], h7 = lst[a + 7];                           \
        const f32x4 wa = *(const f32x4*)(wrecT + (size_t)h0 * H + j0);        \
        const f32x4 wb = *(const f32x4*)(wrecT + (size_t)h1 * H + j0);        \
        const f32x4 wc = *(const f32x4*)(wrecT + (size_t)h2 * H + j0);        \
        const f32x4 wd = *(const f32x4*)(wrecT + (size_t)h3 * H + j0);        \
        const f32x4 we = *(const f32x4*)(wrecT + (size_t)h4 * H + j0);        \
        const f32x4 wf = *(const f32x4*)(wrecT + (size_t)h5 * H + j0);        \
        const f32x4 wg = *(const f32x4*)(wrecT + (size_t)h6 * H + j0);        \
        const f32x4 wh = *(const f32x4*)(wrecT + (size_t)h7 * H + j0);        \
        r0 += wa.x; r1 += wa.y; r2 += wa.z; r3 += wa.w;                       \
        r0 += wb.x; r1 += wb.y; r2 += wb.z; r3 += wb.w;                       \
        r0 += wc.x; r1 += wc.y; r2 += wc.z; r3 += wc.w;                       \
        r0 += wd.x; r1 += wd.y; r2 += wd.z; r3 += wd.w;                       \
        r0 += we.x; r1 += we.y; r2 += we.z; r3 += we.w;                       \
        r0 += wf.x; r1 += wf.y; r2 += wf.z; r3 += wf.w;                       \
        r0 += wg.x; r1 += wg.y; r2 += wg.z; r3 += wg.w;                       \
        r0 += wh.x; r1 += wh.y; r2 += wh.z; r3 += wh.w;                       \
      }                                                                       \
      for (; a < nw; ++a) {                                                   \
        const int h = lst[a];                                                 \
        const f32x4 w4 = *(const f32x4*)(wrecT + (size_t)h * H + j0);         \
        r0 += w4.x; r1 += w4.y; r2 += w4.z; r3 += w4.w;                       \
      }                                                                       \
    }                                                                         \
    const float vd0 = sv0 + C_MEM * (0.0f - sv0 + si0);                       \
    const float vd1 = sv1 + C_MEM * (0.0f - sv1 + si1);                       \
    const float vd2 = sv2 + C_MEM * (0.0f - sv2 + si2);                       \
    const float vd3 = sv3 + C_MEM * (0.0f - sv3 + si3);                       \
    const float id0 = si0 - C_SYN * si0;                                      \
    const float id1 = si1 - C_SYN * si1;                                      \
    const float id2 = si2 - C_SYN * si2;                                      \
    const float id3 = si3 - C_SYN * si3;                                      \
    const float bd0 = sb0 + C_AD * (1.0f - sb0);                              \
    const float bd1 = sb1 + C_AD * (1.0f - sb1);                              \
    const float bd2 = sb2 + C_AD * (1.0f - sb2);                              \
    const float bd3 = sb3 + C_AD * (1.0f - sb3);                              \
    sz0 = ((vd0 - bd0) > 0.0f) ? 1.0f : 0.0f;                                 \
    sz1 = ((vd1 - bd1) > 0.0f) ? 1.0f : 0.0f;                                 \
    sz2 = ((vd2 - bd2) > 0.0f) ? 1.0f : 0.0f;                                 \
    sz3 = ((vd3 - bd3) > 0.0f) ? 1.0f : 0.0f;                                 \
    sv0 = (sz0 > 0.0f) ? 0.0f : vd0;                                          \
    sv1 = (sz1 > 0.0f) ? 0.0f : vd1;                                          \
    sv2 = (sz2 > 0.0f) ? 0.0f : vd2;                                          \
    sv3 = (sz3 > 0.0f) ? 0.0f : vd3;                                          \
    sb0 = (sz0 > 0.0f) ? (bd0 + BETA) : bd0;                                  \
    sb1 = (sz1 > 0.0f) ? (bd1 + BETA) : bd1;                                  \
    sb2 = (sz2 > 0.0f) ? (bd2 + BETA) : bd2;                                  \
    sb3 = (sz3 > 0.0f) ? (bd3 + BETA) : bd3;                                  \
    si0 = (id0 + cc0) + r0;                                                   \
    si1 = (id1 + cc1) + r1;                                                   \
    si2 = (id2 + cc2) + r2;                                                   \
    si3 = (id3 + cc3) + r3;                                                   \
    if (PF) {                                                                 \
      /* next chunk's cur loads (spin until produced by GEMM) */              \
      if ((T) + 1 < T_STEPS) {                                                \
        LOADP8_SPIN(base + (size_t)((T) + 1) * BH);                           \
      }                                                                       \
    }                                                                         \
    *reinterpret_cast<f32x4*>(base + (size_t)(T) * BH) =                      \
        (f32x4){sz0, sz1, sz2, sz3};                                          \
    const unsigned long long m0 = __ballot(sz0 > 0.0f);                       \
    const unsigned long long m1 = __ballot(sz1 > 0.0f);                       \
    const unsigned long long m2 = __ballot(sz2 > 0.0f);                       \
    const unsigned long long m3 = __ballot(sz3 > 0.0f);                       \
    unsigned pos = __builtin_amdgcn_mbcnt_hi((unsigned)(m0 >> 32),            \
                   __builtin_amdgcn_mbcnt_lo((unsigned)m0, 0u));              \
    pos = __builtin_amdgcn_mbcnt_hi((unsigned)(m1 >> 32),                     \
          __builtin_amdgcn_mbcnt_lo((unsigned)m1, pos));                      \
    pos = __builtin_amdgcn_mbcnt_hi((unsigned)(m2 >> 32),                     \
          __builtin_amdgcn_mbcnt_lo((unsigned)m2, pos));                      \
    pos = __builtin_amdgcn_mbcnt_hi((unsigned)(m3 >> 32),                     \
          __builtin_amdgcn_mbcnt_lo((unsigned)m3, pos));                      \
    int* dst = &list[p ^ 1][wave][0];                                         \
    if (sz0 > 0.0f) dst[pos++] = j0 + 0;                                      \
    if (sz1 > 0.0f) dst[pos++] = j0 + 1;                                      \
    if (sz2 > 0.0f) dst[pos++] = j0 + 2;                                      \
    if (sz3 > 0.0f) dst[pos++] = j0 + 3;                                      \
    if (lane == 0)                                                            \
      cnt[p ^ 1][wave] = __popcll(m0) + __popcll(m1) + __popcll(m2) + __popcll(m3); \
    asm volatile("s_waitcnt lgkmcnt(0)" ::: "memory");                        \
    __builtin_amdgcn_s_barrier();                                             \
    p ^= 1;                                                                   \
  }

    for (int t = 0; t < T_STEPS; t += 8) {
        SCAN_STEP(t,     P0, 0);
        SCAN_STEP(t + 1, P1, 0);
        SCAN_STEP(t + 2, P2, 0);
        SCAN_STEP(t + 3, P3, 0);
        SCAN_STEP(t + 4, P4, 0);
        SCAN_STEP(t + 5, P5, 0);
        SCAN_STEP(t + 6, P6, 0);
        SCAN_STEP(t + 7, P7, 1);
    }
#undef SCAN_STEP
#undef LOADP8_SPIN
#undef LDP

    float* fo = io + (size_t)T_STEPS * BH + (size_t)b * H + j0;
    *reinterpret_cast<float4*>(fo)          = make_float4(sz0, sz1, sz2, sz3);
    *reinterpret_cast<float4*>(fo + BH)     = make_float4(sv0, sv1, sv2, sv3);
    *reinterpret_cast<float4*>(fo + 2 * BH) = make_float4(si0, si1, si2, si3);
    *reinterpret_cast<float4*>(fo + 3 * BH) = make_float4(sb0, sb1, sb2, sb3);
}

// ---------------------------------------------------------------------------
extern "C" void kernel_launch(void* const* d_in, const int* in_sizes, int n_in,
                              void* d_out, int out_size, void* d_ws, size_t ws_size,
                              hipStream_t stream) {
    const float* x     = (const float*)d_in[0];
    const float* w_in  = (const float*)d_in[1];
    const float* w_rec = (const float*)d_in[2];
    float* out   = (float*)d_out;
    float* wrecT = (float*)d_ws;

    // arm the sentinel over the cur/z region (first T*BH floats of io)
    hipMemsetAsync(out, 0x7F, (size_t)T_STEPS * BH * sizeof(float), stream);
    transpose1024<<<dim3(H / 32, H / 32), dim3(32, 8), 0, stream>>>(w_rec, wrecT);
    fused_gemm_scan<<<dim3(GRID_BLOCKS), 256, 0, stream>>>(x, w_in, out, wrecT);
}

// Round 8
// 752.993 us; speedup vs baseline: 1.9107x; 1.0064x over previous
//
#include <hip/hip_runtime.h>

typedef float f32x4 __attribute__((ext_vector_type(4)));

#define T_STEPS 512
#define BATCH   64
#define NIN     512
#define H       1024
#define BH      (BATCH * H)   // 65536
#define SENTU   0x7F7F7F7Fu  // sentinel bit pattern (3.39e38f; GEMM can't produce it)

#define BM 128
#define BN 128
#define BK 16
#define LDSS 132
// grid: 344 groups of 8 slots. Slots {0,1}, groups 0..31 -> 64 scan blocks
// (XCDs 0,1; 1 block/CU). Slots {2..7} -> GEMM; slot s owns m-tiles
// mt ≡ (s-2) (mod 6) with the 8 n-tiles of an m-tile consecutive in that
// slot's queue -> each x m-panel is fetched by exactly ONE XCD, and m-tiles
// {6k..6k+5} complete concurrently -> production ascends in t for the scan.
#define GRID_BLOCKS (344 * 8)

// device-coherent (agent-scope) scalar access: bypasses per-XCD caches so
// producer (GEMM blocks, XCD 2-7) and consumer (scan blocks, XCD 0-1) meet
// at the device coherence point. RELAXED: no fences, no cache invalidation
// (critical: keeps wrecT L2-resident on the scan XCDs). R16 lesson: do NOT
// hand-roll these with asm sc-flags — the compiler's atomic path is the
// verified-coherent one (R16's asm variant read stale L2 -> wrong spikes).
__device__ __forceinline__ float ld_agent(const float* p) {
    return __hip_atomic_load(p, __ATOMIC_RELAXED, __HIP_MEMORY_SCOPE_AGENT);
}
__device__ __forceinline__ void st_agent(float* p, float v) {
    __hip_atomic_store(p, v, __ATOMIC_RELAXED, __HIP_MEMORY_SCOPE_AGENT);
}

// ---------------------------------------------------------------------------
// Kernel 1: transpose w_rec [j][h] -> wrecT [h][j]  (4 MB, one-time per call)
// ---------------------------------------------------------------------------
__global__ void transpose1024(const float* __restrict__ in, float* __restrict__ out) {
    __shared__ float tile[32][33];
    const int tx = threadIdx.x, ty = threadIdx.y;
    const int xg = blockIdx.x * 32 + tx;
    const int ybase = blockIdx.y * 32;
#pragma unroll
    for (int r = 0; r < 32; r += 8)
        tile[ty + r][tx] = in[(size_t)(ybase + ty + r) * H + xg];
    __syncthreads();
    const int x2 = blockIdx.y * 32 + tx;
    const int y2base = blockIdx.x * 32;
#pragma unroll
    for (int r = 0; r < 32; r += 8)
        out[(size_t)(y2base + ty + r) * H + x2] = tile[tx][ty + r];
}

// ---------------------------------------------------------------------------
// Fused kernel with XCD partition (R17 = R15-verbatim sync/stores + per-XCD
// m-tile ownership mapping ONLY).
// ---------------------------------------------------------------------------
__global__ void fused_gemm_scan(const float* __restrict__ x,
                                const float* __restrict__ w,
                                float* __restrict__ io,
                                const float* __restrict__ wrecT) {
    // shared memory union: GEMM needs 2*BK*LDSS floats (16896 B), scan needs
    // list[2][4][256] + cnt[2][4] ints (8224 B).
    __shared__ __align__(16) char smem[2 * BK * LDSS * sizeof(float)];

    const int slot = blockIdx.x & 7;
    if (slot >= 2) {
        // ------------------------- GEMM path (R7-verbatim math) -----------
        const int gp = blockIdx.x >> 3;          // group index 0..343
        const int xl = slot - 2;                 // 0..5 == owning-XCD lane
        const int mt = (gp >> 3) * 6 + xl;       // m-tile owned by this XCD
        if (mt >= (T_STEPS * BATCH) / BM) return;
        const int m0 = mt * BM;
        const int n0 = (gp & 7) * BN;
        float* cur = io;

        float (*As)[LDSS] = reinterpret_cast<float (*)[LDSS]>(smem);
        float (*Bs)[LDSS] = reinterpret_cast<float (*)[LDSS]>(smem + BK * LDSS * sizeof(float));

        const int tid = threadIdx.x;
        const int tx = tid & 15, ty = tid >> 4;
        const int tx4 = tx * 4, ty4 = ty * 4;

        float acc[8][8];
#pragma unroll
        for (int i = 0; i < 8; ++i)
#pragma unroll
            for (int j = 0; j < 8; ++j) acc[i][j] = 0.0f;

        const int ar = tid >> 2;
        const int akc = (tid & 3) * 4;

        for (int k0 = 0; k0 < NIN; k0 += BK) {
            const float4 a0 = *reinterpret_cast<const float4*>(&x[(size_t)(m0 + ar) * NIN + k0 + akc]);
            const float4 a1 = *reinterpret_cast<const float4*>(&x[(size_t)(m0 + ar + 64) * NIN + k0 + akc]);
            const float4 b0 = *reinterpret_cast<const float4*>(&w[(size_t)(n0 + ar) * NIN + k0 + akc]);
            const float4 b1 = *reinterpret_cast<const float4*>(&w[(size_t)(n0 + ar + 64) * NIN + k0 + akc]);
            __syncthreads();
            As[akc + 0][ar] = a0.x; As[akc + 1][ar] = a0.y; As[akc + 2][ar] = a0.z; As[akc + 3][ar] = a0.w;
            As[akc + 0][ar + 64] = a1.x; As[akc + 1][ar + 64] = a1.y; As[akc + 2][ar + 64] = a1.z; As[akc + 3][ar + 64] = a1.w;
            Bs[akc + 0][ar] = b0.x; Bs[akc + 1][ar] = b0.y; Bs[akc + 2][ar] = b0.z; Bs[akc + 3][ar] = b0.w;
            Bs[akc + 0][ar + 64] = b1.x; Bs[akc + 1][ar + 64] = b1.y; Bs[akc + 2][ar + 64] = b1.z; Bs[akc + 3][ar + 64] = b1.w;
            __syncthreads();

#pragma unroll
            for (int kk = 0; kk < BK; ++kk) {
                const float4 av0 = *reinterpret_cast<const float4*>(&As[kk][ty4]);
                const float4 av1 = *reinterpret_cast<const float4*>(&As[kk][ty4 + 64]);
                const float4 bv0 = *reinterpret_cast<const float4*>(&Bs[kk][tx4]);
                const float4 bv1 = *reinterpret_cast<const float4*>(&Bs[kk][tx4 + 64]);
                const float ar_[8] = {av0.x, av0.y, av0.z, av0.w, av1.x, av1.y, av1.z, av1.w};
                const float br_[8] = {bv0.x, bv0.y, bv0.z, bv0.w, bv1.x, bv1.y, bv1.z, bv1.w};
#pragma unroll
                for (int i = 0; i < 8; ++i)
#pragma unroll
                    for (int j = 0; j < 8; ++j)
                        acc[i][j] = fmaf(ar_[i], br_[j], acc[i][j]);
            }
        }

        // epilogue: agent-scope scalar stores (R15-verbatim, proven coherent)
#pragma unroll
        for (int gi = 0; gi < 2; ++gi)
#pragma unroll
            for (int ii = 0; ii < 4; ++ii) {
                const int i = gi * 4 + ii;
                const int row = m0 + ty4 + ii + gi * 64;
                float* dst = &cur[(size_t)row * H + n0 + tx4];
                st_agent(dst + 0,  acc[i][0]); st_agent(dst + 1,  acc[i][1]);
                st_agent(dst + 2,  acc[i][2]); st_agent(dst + 3,  acc[i][3]);
                st_agent(dst + 64, acc[i][4]); st_agent(dst + 65, acc[i][5]);
                st_agent(dst + 66, acc[i][6]); st_agent(dst + 67, acc[i][7]);
            }
        return;
    }

    // ----------------------------- scan path (R8-verbatim) ----------------
    if (blockIdx.x >= 256) return;                 // only first 32 groups
    const int b = (blockIdx.x >> 3) * 2 + slot;    // 0..63
    const int tid = threadIdx.x;
    const int wave = tid >> 6, lane = tid & 63;
    const int j0 = tid * 4;

    int (*list)[4][256] = reinterpret_cast<int (*)[4][256]>(smem);          // 8192 B
    int (*cnt)[4]       = reinterpret_cast<int (*)[4]>(smem + 8192);        // 32 B

    float sv0 = 0.f, sv1 = 0.f, sv2 = 0.f, sv3 = 0.f;
    float si0 = 0.f, si1 = 0.f, si2 = 0.f, si3 = 0.f;
    float sb0 = 1.f, sb1 = 1.f, sb2 = 1.f, sb3 = 1.f;
    float sz0 = 0.f, sz1 = 0.f, sz2 = 0.f, sz3 = 0.f;
    int p = 0;

    const float C_MEM = (float)(1e-3 * 100.0);
    const float C_SYN = (float)(1e-3 * 200.0);
    const float C_AD  = (float)(1e-3 * (1.0 / 800.0));
    const float BETA  = 1.8f;

    float* base = io + (size_t)b * H + j0;

    if (lane == 0) cnt[0][wave] = 0;
    asm volatile("s_waitcnt lgkmcnt(0)" ::: "memory");
    __builtin_amdgcn_s_barrier();

    f32x4 P0, P1, P2, P3, P4, P5, P6, P7;

// one prefetch register: 4 agent-scope scalar loads + sentinel check
#define LDP(REG, KK)                                                          \
      REG.x = ld_agent(pb_ + (size_t)(KK) * BH + 0);                          \
      REG.y = ld_agent(pb_ + (size_t)(KK) * BH + 1);                          \
      REG.z = ld_agent(pb_ + (size_t)(KK) * BH + 2);                          \
      REG.w = ld_agent(pb_ + (size_t)(KK) * BH + 3);                          \
      bad_ |= (unsigned)(__float_as_uint(REG.x) == SENTU);                    \
      bad_ |= (unsigned)(__float_as_uint(REG.y) == SENTU);                    \
      bad_ |= (unsigned)(__float_as_uint(REG.z) == SENTU);                    \
      bad_ |= (unsigned)(__float_as_uint(REG.w) == SENTU);

// spin (bounded) until the next 8 steps of cur are all produced by the GEMM
#define LOADP8_SPIN(PBASE)                                                    \
  { const float* pb_ = (PBASE);                                               \
    for (int tries_ = 0; tries_ < (1 << 14); ++tries_) {                      \
      unsigned bad_ = 0u;                                                     \
      LDP(P0, 0) LDP(P1, 1) LDP(P2, 2) LDP(P3, 3)                             \
      LDP(P4, 4) LDP(P5, 5) LDP(P6, 6) LDP(P7, 7)                             \
      if (__ballot(bad_ != 0u) == 0ull) break;                                \
      __builtin_amdgcn_s_sleep(8);                                            \
    } }

    // chunk prefetch: 8 steps of cur (spin until GEMM has produced them)
    LOADP8_SPIN(base);

#define SCAN_STEP(T, CREG, PF)                                                \
  {                                                                           \
    const float cc0 = CREG.x, cc1 = CREG.y, cc2 = CREG.z, cc3 = CREG.w;       \
    const int4 cn = *reinterpret_cast<const int4*>(&cnt[p][0]);               \
    float r0 = 0.f, r1 = 0.f, r2 = 0.f, r3 = 0.f;                             \
    _Pragma("unroll")                                                         \
    for (int w = 0; w < 4; ++w) {                                             \
      const int nw = (w == 0) ? cn.x : (w == 1) ? cn.y : (w == 2) ? cn.z : cn.w; \
      const int* lst = &list[p][w][0];                                        \
      int a = 0;                                                              \
      for (; a + 8 <= nw; a += 8) {                                           \
        const int h0 = lst[a],     h1 = lst[a + 1];                           \
        const int h2 = lst[a + 2], h3 = lst[a + 3];                           \
        const int h4 = lst[a + 4], h5 = lst[a + 5];                           \
        const int h6 = lst[a + 6], h7 = lst[a + 7];                           \
        const f32x4 wa = *(const f32x4*)(wrecT + (size_t)h0 * H + j0);        \
        const f32x4 wb = *(const f32x4*)(wrecT + (size_t)h1 * H + j0);        \
        const f32x4 wc = *(const f32x4*)(wrecT + (size_t)h2 * H + j0);        \
        const f32x4 wd = *(const f32x4*)(wrecT + (size_t)h3 * H + j0);        \
        const f32x4 we = *(const f32x4*)(wrecT + (size_t)h4 * H + j0);        \
        const f32x4 wf = *(const f32x4*)(wrecT + (size_t)h5 * H + j0);        \
        const f32x4 wg = *(const f32x4*)(wrecT + (size_t)h6 * H + j0);        \
        const f32x4 wh = *(const f32x4*)(wrecT + (size_t)h7 * H + j0);        \
        r0 += wa.x; r1 += wa.y; r2 += wa.z; r3 += wa.w;                       \
        r0 += wb.x; r1 += wb.y; r2 += wb.z; r3 += wb.w;                       \
        r0 += wc.x; r1 += wc.y; r2 += wc.z; r3 += wc.w;                       \
        r0 += wd.x; r1 += wd.y; r2 += wd.z; r3 += wd.w;                       \
        r0 += we.x; r1 += we.y; r2 += we.z; r3 += we.w;                       \
        r0 += wf.x; r1 += wf.y; r2 += wf.z; r3 += wf.w;                       \
        r0 += wg.x; r1 += wg.y; r2 += wg.z; r3 += wg.w;                       \
        r0 += wh.x; r1 += wh.y; r2 += wh.z; r3 += wh.w;                       \
      }                                                                       \
      for (; a < nw; ++a) {                                                   \
        const int h = lst[a];                                                 \
        const f32x4 w4 = *(const f32x4*)(wrecT + (size_t)h * H + j0);         \
        r0 += w4.x; r1 += w4.y; r2 += w4.z; r3 += w4.w;                       \
      }                                                                       \
    }                                                                         \
    const float vd0 = sv0 + C_MEM * (0.0f - sv0 + si0);                       \
    const float vd1 = sv1 + C_MEM * (0.0f - sv1 + si1);                       \
    const float vd2 = sv2 + C_MEM * (0.0f - sv2 + si2);                       \
    const float vd3 = sv3 + C_MEM * (0.0f - sv3 + si3);                       \
    const float id0 = si0 - C_SYN * si0;                                      \
    const float id1 = si1 - C_SYN * si1;                                      \
    const float id2 = si2 - C_SYN * si2;                                      \
    const float id3 = si3 - C_SYN * si3;                                      \
    const float bd0 = sb0 + C_AD * (1.0f - sb0);                              \
    const float bd1 = sb1 + C_AD * (1.0f - sb1);                              \
    const float bd2 = sb2 + C_AD * (1.0f - sb2);                              \
    const float bd3 = sb3 + C_AD * (1.0f - sb3);                              \
    sz0 = ((vd0 - bd0) > 0.0f) ? 1.0f : 0.0f;                                 \
    sz1 = ((vd1 - bd1) > 0.0f) ? 1.0f : 0.0f;                                 \
    sz2 = ((vd2 - bd2) > 0.0f) ? 1.0f : 0.0f;                                 \
    sz3 = ((vd3 - bd3) > 0.0f) ? 1.0f : 0.0f;                                 \
    sv0 = (sz0 > 0.0f) ? 0.0f : vd0;                                          \
    sv1 = (sz1 > 0.0f) ? 0.0f : vd1;                                          \
    sv2 = (sz2 > 0.0f) ? 0.0f : vd2;                                          \
    sv3 = (sz3 > 0.0f) ? 0.0f : vd3;                                          \
    sb0 = (sz0 > 0.0f) ? (bd0 + BETA) : bd0;                                  \
    sb1 = (sz1 > 0.0f) ? (bd1 + BETA) : bd1;                                  \
    sb2 = (sz2 > 0.0f) ? (bd2 + BETA) : bd2;                                  \
    sb3 = (sz3 > 0.0f) ? (bd3 + BETA) : bd3;                                  \
    si0 = (id0 + cc0) + r0;                                                   \
    si1 = (id1 + cc1) + r1;                                                   \
    si2 = (id2 + cc2) + r2;                                                   \
    si3 = (id3 + cc3) + r3;                                                   \
    if (PF) {                                                                 \
      /* next chunk's cur loads (spin until produced by GEMM) */              \
      if ((T) + 1 < T_STEPS) {                                                \
        LOADP8_SPIN(base + (size_t)((T) + 1) * BH);                           \
      }                                                                       \
    }                                                                         \
    *reinterpret_cast<f32x4*>(base + (size_t)(T) * BH) =                      \
        (f32x4){sz0, sz1, sz2, sz3};                                          \
    const unsigned long long m0 = __ballot(sz0 > 0.0f);                       \
    const unsigned long long m1 = __ballot(sz1 > 0.0f);                       \
    const unsigned long long m2 = __ballot(sz2 > 0.0f);                       \
    const unsigned long long m3 = __ballot(sz3 > 0.0f);                       \
    unsigned pos = __builtin_amdgcn_mbcnt_hi((unsigned)(m0 >> 32),            \
                   __builtin_amdgcn_mbcnt_lo((unsigned)m0, 0u));              \
    pos = __builtin_amdgcn_mbcnt_hi((unsigned)(m1 >> 32),                     \
          __builtin_amdgcn_mbcnt_lo((unsigned)m1, pos));                      \
    pos = __builtin_amdgcn_mbcnt_hi((unsigned)(m2 >> 32),                     \
          __builtin_amdgcn_mbcnt_lo((unsigned)m2, pos));                      \
    pos = __builtin_amdgcn_mbcnt_hi((unsigned)(m3 >> 32),                     \
          __builtin_amdgcn_mbcnt_lo((unsigned)m3, pos));                      \
    int* dst = &list[p ^ 1][wave][0];                                         \
    if (sz0 > 0.0f) dst[pos++] = j0 + 0;                                      \
    if (sz1 > 0.0f) dst[pos++] = j0 + 1;                                      \
    if (sz2 > 0.0f) dst[pos++] = j0 + 2;                                      \
    if (sz3 > 0.0f) dst[pos++] = j0 + 3;                                      \
    if (lane == 0)                                                            \
      cnt[p ^ 1][wave] = __popcll(m0) + __popcll(m1) + __popcll(m2) + __popcll(m3); \
    asm volatile("s_waitcnt lgkmcnt(0)" ::: "memory");                        \
    __builtin_amdgcn_s_barrier();                                             \
    p ^= 1;                                                                   \
  }

    for (int t = 0; t < T_STEPS; t += 8) {
        SCAN_STEP(t,     P0, 0);
        SCAN_STEP(t + 1, P1, 0);
        SCAN_STEP(t + 2, P2, 0);
        SCAN_STEP(t + 3, P3, 0);
        SCAN_STEP(t + 4, P4, 0);
        SCAN_STEP(t + 5, P5, 0);
        SCAN_STEP(t + 6, P6, 0);
        SCAN_STEP(t + 7, P7, 1);
    }
#undef SCAN_STEP
#undef LOADP8_SPIN
#undef LDP

    float* fo = io + (size_t)T_STEPS * BH + (size_t)b * H + j0;
    *reinterpret_cast<float4*>(fo)          = make_float4(sz0, sz1, sz2, sz3);
    *reinterpret_cast<float4*>(fo + BH)     = make_float4(sv0, sv1, sv2, sv3);
    *reinterpret_cast<float4*>(fo + 2 * BH) = make_float4(si0, si1, si2, si3);
    *reinterpret_cast<float4*>(fo + 3 * BH) = make_float4(sb0, sb1, sb2, sb3);
}

// ---------------------------------------------------------------------------
extern "C" void kernel_launch(void* const* d_in, const int* in_sizes, int n_in,
                              void* d_out, int out_size, void* d_ws, size_t ws_size,
                              hipStream_t stream) {
    const float* x     = (const float*)d_in[0];
    const float* w_in  = (const float*)d_in[1];
    const float* w_rec = (const float*)d_in[2];
    float* out   = (float*)d_out;
    float* wrecT = (float*)d_ws;

    // arm the sentinel over the cur/z region (first T*BH floats of io)
    hipMemsetAsync(out, 0x7F, (size_t)T_STEPS * BH * sizeof(float), stream);
    transpose1024<<<dim3(H / 32, H / 32), dim3(32, 8), 0, stream>>>(w_rec, wrecT);
    fused_gemm_scan<<<dim3(GRID_BLOCKS), 256, 0, stream>>>(x, w_in, out, wrecT);
}

// Round 9
// 737.172 us; speedup vs baseline: 1.9518x; 1.0215x over previous
//
#include <hip/hip_runtime.h>

typedef float f32x4 __attribute__((ext_vector_type(4)));

#define T_STEPS 512
#define BATCH   64
#define NIN     512
#define H       1024
#define BH      (BATCH * H)   // 65536
#define SENTU   0x7F7F7F7Fu  // sentinel bit pattern (3.39e38f; GEMM can't produce it)

#define BM 128
#define BN 128
#define BK 16
#define LDSS 132
#define NUM_ITEMS ((T_STEPS * BATCH / BM) * (H / BN))   // 2048 work items
#define PERS_BLOCKS 384                                  // 64 groups x 6 slots
// grid: 64 groups of 8 slots. Slots {0,1}, groups 0..31 -> 64 scan blocks
// (XCDs 0,1; 1 block/CU; wrecT L2-resident there). Slots {2..7} -> 384
// PERSISTENT GEMM blocks (2/CU on XCDs 2..7); block pb sweeps items
// w = pb, pb+384, ... ascending -> production of cur STREAMS in ascending
// timestep batches of 96 steps (fixes R15/R17's batched-completion stall,
// where ~8 resident blocks/CU all finished together near the end).
#define GRID_BLOCKS (64 * 8)

// device-coherent (agent-scope) scalar access: bypasses per-XCD caches so
// producer (GEMM, XCD 2-7) and consumer (scan, XCD 0-1) meet at the device
// coherence point. RELAXED: no fences, no cache invalidation (keeps wrecT
// L2-resident on scan XCDs). R16 lesson: do NOT hand-roll with asm sc-flags.
__device__ __forceinline__ float ld_agent(const float* p) {
    return __hip_atomic_load(p, __ATOMIC_RELAXED, __HIP_MEMORY_SCOPE_AGENT);
}
__device__ __forceinline__ void st_agent(float* p, float v) {
    __hip_atomic_store(p, v, __ATOMIC_RELAXED, __HIP_MEMORY_SCOPE_AGENT);
}

// ---------------------------------------------------------------------------
// Kernel 1: transpose w_rec [j][h] -> wrecT [h][j]  (4 MB, one-time per call)
// ---------------------------------------------------------------------------
__global__ void transpose1024(const float* __restrict__ in, float* __restrict__ out) {
    __shared__ float tile[32][33];
    const int tx = threadIdx.x, ty = threadIdx.y;
    const int xg = blockIdx.x * 32 + tx;
    const int ybase = blockIdx.y * 32;
#pragma unroll
    for (int r = 0; r < 32; r += 8)
        tile[ty + r][tx] = in[(size_t)(ybase + ty + r) * H + xg];
    __syncthreads();
    const int x2 = blockIdx.y * 32 + tx;
    const int y2base = blockIdx.x * 32;
#pragma unroll
    for (int r = 0; r < 32; r += 8)
        out[(size_t)(y2base + ty + r) * H + x2] = tile[tx][ty + r];
}

// ---------------------------------------------------------------------------
// Fused kernel (R18 = R17 + persistent streaming GEMM blocks ONLY).
// ---------------------------------------------------------------------------
__global__ void fused_gemm_scan(const float* __restrict__ x,
                                const float* __restrict__ w,
                                float* __restrict__ io,
                                const float* __restrict__ wrecT) {
    // shared memory union: GEMM needs 2*BK*LDSS floats (16896 B), scan needs
    // list[2][4][256] + cnt[2][4] ints (8224 B).
    __shared__ __align__(16) char smem[2 * BK * LDSS * sizeof(float)];

    const int slot = blockIdx.x & 7;
    if (slot >= 2) {
        // ------------- persistent GEMM path (R7-verbatim tile math) -------
        const int gp = blockIdx.x >> 3;              // group 0..63
        const int pb = gp * 6 + (slot - 2);          // persistent id 0..383
        float* cur = io;

        float (*As)[LDSS] = reinterpret_cast<float (*)[LDSS]>(smem);
        float (*Bs)[LDSS] = reinterpret_cast<float (*)[LDSS]>(smem + BK * LDSS * sizeof(float));

        const int tid = threadIdx.x;
        const int tx = tid & 15, ty = tid >> 4;
        const int tx4 = tx * 4, ty4 = ty * 4;
        const int ar = tid >> 2;
        const int akc = (tid & 3) * 4;

        for (int wi = pb; wi < NUM_ITEMS; wi += PERS_BLOCKS) {
            const int m0 = (wi >> 3) * BM;           // ascending timestep
            const int n0 = (wi & 7) * BN;

            float acc[8][8];
#pragma unroll
            for (int i = 0; i < 8; ++i)
#pragma unroll
                for (int j = 0; j < 8; ++j) acc[i][j] = 0.0f;

            for (int k0 = 0; k0 < NIN; k0 += BK) {
                const float4 a0 = *reinterpret_cast<const float4*>(&x[(size_t)(m0 + ar) * NIN + k0 + akc]);
                const float4 a1 = *reinterpret_cast<const float4*>(&x[(size_t)(m0 + ar + 64) * NIN + k0 + akc]);
                const float4 b0 = *reinterpret_cast<const float4*>(&w[(size_t)(n0 + ar) * NIN + k0 + akc]);
                const float4 b1 = *reinterpret_cast<const float4*>(&w[(size_t)(n0 + ar + 64) * NIN + k0 + akc]);
                __syncthreads();
                As[akc + 0][ar] = a0.x; As[akc + 1][ar] = a0.y; As[akc + 2][ar] = a0.z; As[akc + 3][ar] = a0.w;
                As[akc + 0][ar + 64] = a1.x; As[akc + 1][ar + 64] = a1.y; As[akc + 2][ar + 64] = a1.z; As[akc + 3][ar + 64] = a1.w;
                Bs[akc + 0][ar] = b0.x; Bs[akc + 1][ar] = b0.y; Bs[akc + 2][ar] = b0.z; Bs[akc + 3][ar] = b0.w;
                Bs[akc + 0][ar + 64] = b1.x; Bs[akc + 1][ar + 64] = b1.y; Bs[akc + 2][ar + 64] = b1.z; Bs[akc + 3][ar + 64] = b1.w;
                __syncthreads();

#pragma unroll
                for (int kk = 0; kk < BK; ++kk) {
                    const float4 av0 = *reinterpret_cast<const float4*>(&As[kk][ty4]);
                    const float4 av1 = *reinterpret_cast<const float4*>(&As[kk][ty4 + 64]);
                    const float4 bv0 = *reinterpret_cast<const float4*>(&Bs[kk][tx4]);
                    const float4 bv1 = *reinterpret_cast<const float4*>(&Bs[kk][tx4 + 64]);
                    const float ar_[8] = {av0.x, av0.y, av0.z, av0.w, av1.x, av1.y, av1.z, av1.w};
                    const float br_[8] = {bv0.x, bv0.y, bv0.z, bv0.w, bv1.x, bv1.y, bv1.z, bv1.w};
#pragma unroll
                    for (int i = 0; i < 8; ++i)
#pragma unroll
                        for (int j = 0; j < 8; ++j)
                            acc[i][j] = fmaf(ar_[i], br_[j], acc[i][j]);
                }
            }

            // epilogue: agent-scope scalar stores (R15/R17-verbatim, coherent)
#pragma unroll
            for (int gi = 0; gi < 2; ++gi)
#pragma unroll
                for (int ii = 0; ii < 4; ++ii) {
                    const int i = gi * 4 + ii;
                    const int row = m0 + ty4 + ii + gi * 64;
                    float* dst = &cur[(size_t)row * H + n0 + tx4];
                    st_agent(dst + 0,  acc[i][0]); st_agent(dst + 1,  acc[i][1]);
                    st_agent(dst + 2,  acc[i][2]); st_agent(dst + 3,  acc[i][3]);
                    st_agent(dst + 64, acc[i][4]); st_agent(dst + 65, acc[i][5]);
                    st_agent(dst + 66, acc[i][6]); st_agent(dst + 67, acc[i][7]);
                }
        }
        return;
    }

    // ----------------------------- scan path (R8-verbatim) ----------------
    if (blockIdx.x >= 256) return;                 // only first 32 groups
    const int b = (blockIdx.x >> 3) * 2 + slot;    // 0..63
    const int tid = threadIdx.x;
    const int wave = tid >> 6, lane = tid & 63;
    const int j0 = tid * 4;

    int (*list)[4][256] = reinterpret_cast<int (*)[4][256]>(smem);          // 8192 B
    int (*cnt)[4]       = reinterpret_cast<int (*)[4]>(smem + 8192);        // 32 B

    float sv0 = 0.f, sv1 = 0.f, sv2 = 0.f, sv3 = 0.f;
    float si0 = 0.f, si1 = 0.f, si2 = 0.f, si3 = 0.f;
    float sb0 = 1.f, sb1 = 1.f, sb2 = 1.f, sb3 = 1.f;
    float sz0 = 0.f, sz1 = 0.f, sz2 = 0.f, sz3 = 0.f;
    int p = 0;

    const float C_MEM = (float)(1e-3 * 100.0);
    const float C_SYN = (float)(1e-3 * 200.0);
    const float C_AD  = (float)(1e-3 * (1.0 / 800.0));
    const float BETA  = 1.8f;

    float* base = io + (size_t)b * H + j0;

    if (lane == 0) cnt[0][wave] = 0;
    asm volatile("s_waitcnt lgkmcnt(0)" ::: "memory");
    __builtin_amdgcn_s_barrier();

    f32x4 P0, P1, P2, P3, P4, P5, P6, P7;

// one prefetch register: 4 agent-scope scalar loads + sentinel check
#define LDP(REG, KK)                                                          \
      REG.x = ld_agent(pb_ + (size_t)(KK) * BH + 0);                          \
      REG.y = ld_agent(pb_ + (size_t)(KK) * BH + 1);                          \
      REG.z = ld_agent(pb_ + (size_t)(KK) * BH + 2);                          \
      REG.w = ld_agent(pb_ + (size_t)(KK) * BH + 3);                          \
      bad_ |= (unsigned)(__float_as_uint(REG.x) == SENTU);                    \
      bad_ |= (unsigned)(__float_as_uint(REG.y) == SENTU);                    \
      bad_ |= (unsigned)(__float_as_uint(REG.z) == SENTU);                    \
      bad_ |= (unsigned)(__float_as_uint(REG.w) == SENTU);

// spin (bounded) until the next 8 steps of cur are all produced by the GEMM
#define LOADP8_SPIN(PBASE)                                                    \
  { const float* pb_ = (PBASE);                                               \
    for (int tries_ = 0; tries_ < (1 << 14); ++tries_) {                      \
      unsigned bad_ = 0u;                                                     \
      LDP(P0, 0) LDP(P1, 1) LDP(P2, 2) LDP(P3, 3)                             \
      LDP(P4, 4) LDP(P5, 5) LDP(P6, 6) LDP(P7, 7)                             \
      if (__ballot(bad_ != 0u) == 0ull) break;                                \
      __builtin_amdgcn_s_sleep(8);                                            \
    } }

    // chunk prefetch: 8 steps of cur (spin until GEMM has produced them)
    LOADP8_SPIN(base);

#define SCAN_STEP(T, CREG, PF)                                                \
  {                                                                           \
    const float cc0 = CREG.x, cc1 = CREG.y, cc2 = CREG.z, cc3 = CREG.w;       \
    const int4 cn = *reinterpret_cast<const int4*>(&cnt[p][0]);               \
    float r0 = 0.f, r1 = 0.f, r2 = 0.f, r3 = 0.f;                             \
    _Pragma("unroll")                                                         \
    for (int w = 0; w < 4; ++w) {                                             \
      const int nw = (w == 0) ? cn.x : (w == 1) ? cn.y : (w == 2) ? cn.z : cn.w; \
      const int* lst = &list[p][w][0];                                        \
      int a = 0;                                                              \
      for (; a + 8 <= nw; a += 8) {                                           \
        const int h0 = lst[a],     h1 = lst[a + 1];                           \
        const int h2 = lst[a + 2], h3 = lst[a + 3];                           \
        const int h4 = lst[a + 4], h5 = lst[a + 5];                           \
        const int h6 = lst[a + 6], h7 = lst[a + 7];                           \
        const f32x4 wa = *(const f32x4*)(wrecT + (size_t)h0 * H + j0);        \
        const f32x4 wb = *(const f32x4*)(wrecT + (size_t)h1 * H + j0);        \
        const f32x4 wc = *(const f32x4*)(wrecT + (size_t)h2 * H + j0);        \
        const f32x4 wd = *(const f32x4*)(wrecT + (size_t)h3 * H + j0);        \
        const f32x4 we = *(const f32x4*)(wrecT + (size_t)h4 * H + j0);        \
        const f32x4 wf = *(const f32x4*)(wrecT + (size_t)h5 * H + j0);        \
        const f32x4 wg = *(const f32x4*)(wrecT + (size_t)h6 * H + j0);        \
        const f32x4 wh = *(const f32x4*)(wrecT + (size_t)h7 * H + j0);        \
        r0 += wa.x; r1 += wa.y; r2 += wa.z; r3 += wa.w;                       \
        r0 += wb.x; r1 += wb.y; r2 += wb.z; r3 += wb.w;                       \
        r0 += wc.x; r1 += wc.y; r2 += wc.z; r3 += wc.w;                       \
        r0 += wd.x; r1 += wd.y; r2 += wd.z; r3 += wd.w;                       \
        r0 += we.x; r1 += we.y; r2 += we.z; r3 += we.w;                       \
        r0 += wf.x; r1 += wf.y; r2 += wf.z; r3 += wf.w;                       \
        r0 += wg.x; r1 += wg.y; r2 += wg.z; r3 += wg.w;                       \
        r0 += wh.x; r1 += wh.y; r2 += wh.z; r3 += wh.w;                       \
      }                                                                       \
      for (; a < nw; ++a) {                                                   \
        const int h = lst[a];                                                 \
        const f32x4 w4 = *(const f32x4*)(wrecT + (size_t)h * H + j0);         \
        r0 += w4.x; r1 += w4.y; r2 += w4.z; r3 += w4.w;                       \
      }                                                                       \
    }                                                                         \
    const float vd0 = sv0 + C_MEM * (0.0f - sv0 + si0);                       \
    const float vd1 = sv1 + C_MEM * (0.0f - sv1 + si1);                       \
    const float vd2 = sv2 + C_MEM * (0.0f - sv2 + si2);                       \
    const float vd3 = sv3 + C_MEM * (0.0f - sv3 + si3);                       \
    const float id0 = si0 - C_SYN * si0;                                      \
    const float id1 = si1 - C_SYN * si1;                                      \
    const float id2 = si2 - C_SYN * si2;                                      \
    const float id3 = si3 - C_SYN * si3;                                      \
    const float bd0 = sb0 + C_AD * (1.0f - sb0);                              \
    const float bd1 = sb1 + C_AD * (1.0f - sb1);                              \
    const float bd2 = sb2 + C_AD * (1.0f - sb2);                              \
    const float bd3 = sb3 + C_AD * (1.0f - sb3);                              \
    sz0 = ((vd0 - bd0) > 0.0f) ? 1.0f : 0.0f;                                 \
    sz1 = ((vd1 - bd1) > 0.0f) ? 1.0f : 0.0f;                                 \
    sz2 = ((vd2 - bd2) > 0.0f) ? 1.0f : 0.0f;                                 \
    sz3 = ((vd3 - bd3) > 0.0f) ? 1.0f : 0.0f;                                 \
    sv0 = (sz0 > 0.0f) ? 0.0f : vd0;                                          \
    sv1 = (sz1 > 0.0f) ? 0.0f : vd1;                                          \
    sv2 = (sz2 > 0.0f) ? 0.0f : vd2;                                          \
    sv3 = (sz3 > 0.0f) ? 0.0f : vd3;                                          \
    sb0 = (sz0 > 0.0f) ? (bd0 + BETA) : bd0;                                  \
    sb1 = (sz1 > 0.0f) ? (bd1 + BETA) : bd1;                                  \
    sb2 = (sz2 > 0.0f) ? (bd2 + BETA) : bd2;                                  \
    sb3 = (sz3 > 0.0f) ? (bd3 + BETA) : bd3;                                  \
    si0 = (id0 + cc0) + r0;                                                   \
    si1 = (id1 + cc1) + r1;                                                   \
    si2 = (id2 + cc2) + r2;                                                   \
    si3 = (id3 + cc3) + r3;                                                   \
    if (PF) {                                                                 \
      /* next chunk's cur loads (spin until produced by GEMM) */              \
      if ((T) + 1 < T_STEPS) {                                                \
        LOADP8_SPIN(base + (size_t)((T) + 1) * BH);                           \
      }                                                                       \
    }                                                                         \
    *reinterpret_cast<f32x4*>(base + (size_t)(T) * BH) =                      \
        (f32x4){sz0, sz1, sz2, sz3};                                          \
    const unsigned long long m0 = __ballot(sz0 > 0.0f);                       \
    const unsigned long long m1 = __ballot(sz1 > 0.0f);                       \
    const unsigned long long m2 = __ballot(sz2 > 0.0f);                       \
    const unsigned long long m3 = __ballot(sz3 > 0.0f);                       \
    unsigned pos = __builtin_amdgcn_mbcnt_hi((unsigned)(m0 >> 32),            \
                   __builtin_amdgcn_mbcnt_lo((unsigned)m0, 0u));              \
    pos = __builtin_amdgcn_mbcnt_hi((unsigned)(m1 >> 32),                     \
          __builtin_amdgcn_mbcnt_lo((unsigned)m1, pos));                      \
    pos = __builtin_amdgcn_mbcnt_hi((unsigned)(m2 >> 32),                     \
          __builtin_amdgcn_mbcnt_lo((unsigned)m2, pos));                      \
    pos = __builtin_amdgcn_mbcnt_hi((unsigned)(m3 >> 32),                     \
          __builtin_amdgcn_mbcnt_lo((unsigned)m3, pos));                      \
    int* dst = &list[p ^ 1][wave][0];                                         \
    if (sz0 > 0.0f) dst[pos++] = j0 + 0;                                      \
    if (sz1 > 0.0f) dst[pos++] = j0 + 1;                                      \
    if (sz2 > 0.0f) dst[pos++] = j0 + 2;                                      \
    if (sz3 > 0.0f) dst[pos++] = j0 + 3;                                      \
    if (lane == 0)                                                            \
      cnt[p ^ 1][wave] = __popcll(m0) + __popcll(m1) + __popcll(m2) + __popcll(m3); \
    asm volatile("s_waitcnt lgkmcnt(0)" ::: "memory");                        \
    __builtin_amdgcn_s_barrier();                                             \
    p ^= 1;                                                                   \
  }

    for (int t = 0; t < T_STEPS; t += 8) {
        SCAN_STEP(t,     P0, 0);
        SCAN_STEP(t + 1, P1, 0);
        SCAN_STEP(t + 2, P2, 0);
        SCAN_STEP(t + 3, P3, 0);
        SCAN_STEP(t + 4, P4, 0);
        SCAN_STEP(t + 5, P5, 0);
        SCAN_STEP(t + 6, P6, 0);
        SCAN_STEP(t + 7, P7, 1);
    }
#undef SCAN_STEP
#undef LOADP8_SPIN
#undef LDP

    float* fo = io + (size_t)T_STEPS * BH + (size_t)b * H + j0;
    *reinterpret_cast<float4*>(fo)          = make_float4(sz0, sz1, sz2, sz3);
    *reinterpret_cast<float4*>(fo + BH)     = make_float4(sv0, sv1, sv2, sv3);
    *reinterpret_cast<float4*>(fo + 2 * BH) = make_float4(si0, si1, si2, si3);
    *reinterpret_cast<float4*>(fo + 3 * BH) = make_float4(sb0, sb1, sb2, sb3);
}

// ---------------------------------------------------------------------------
extern "C" void kernel_launch(void* const* d_in, const int* in_sizes, int n_in,
                              void* d_out, int out_size, void* d_ws, size_t ws_size,
                              hipStream_t stream) {
    const float* x     = (const float*)d_in[0];
    const float* w_in  = (const float*)d_in[1];
    const float* w_rec = (const float*)d_in[2];
    float* out   = (float*)d_out;
    float* wrecT = (float*)d_ws;

    // arm the sentinel over the cur/z region (first T*BH floats of io)
    hipMemsetAsync(out, 0x7F, (size_t)T_STEPS * BH * sizeof(float), stream);
    transpose1024<<<dim3(H / 32, H / 32), dim3(32, 8), 0, stream>>>(w_rec, wrecT);
    fused_gemm_scan<<<dim3(GRID_BLOCKS), 256, 0, stream>>>(x, w_in, out, wrecT);
}

// Round 10
// 736.000 us; speedup vs baseline: 1.9549x; 1.0016x over previous
//
#include <hip/hip_runtime.h>

typedef float f32x4 __attribute__((ext_vector_type(4)));

#define T_STEPS 512
#define BATCH   64
#define NIN     512
#define H       1024
#define BH      (BATCH * H)   // 65536
#define SENTU   0x7F7F7F7Fu  // sentinel bit pattern (3.39e38f; GEMM can't produce it)

#define BM 128
#define BN 128
#define BK 16
#define LDSS 132
#define NUM_ITEMS ((T_STEPS * BATCH / BM) * (H / BN))   // 2048 work items
#define PERS_BLOCKS 384                                  // 64 groups x 6 slots
// grid: 64 groups of 8 slots. Slots {0,1}, groups 0..31 -> 64 scan blocks
// (XCDs 0,1; 1 block/CU; wrecT L2-resident there). Slots {2..7} -> 384
// PERSISTENT GEMM blocks (2/CU on XCDs 2..7); block pb sweeps items
// w = pb, pb+384, ... ascending -> production of cur STREAMS in ascending
// timestep batches of 96 steps. R19: the K-loop is register double-buffered
// (issue next K-tile's global loads BEFORE compute) so the 2-blocks/CU
// configuration is no longer staging-latency-bound (R18's residual).
#define GRID_BLOCKS (64 * 8)

// device-coherent (agent-scope) scalar access: bypasses per-XCD caches so
// producer (GEMM, XCD 2-7) and consumer (scan, XCD 0-1) meet at the device
// coherence point. RELAXED: no fences, no cache invalidation (keeps wrecT
// L2-resident on scan XCDs). R16 lesson: do NOT hand-roll with asm sc-flags.
__device__ __forceinline__ float ld_agent(const float* p) {
    return __hip_atomic_load(p, __ATOMIC_RELAXED, __HIP_MEMORY_SCOPE_AGENT);
}
__device__ __forceinline__ void st_agent(float* p, float v) {
    __hip_atomic_store(p, v, __ATOMIC_RELAXED, __HIP_MEMORY_SCOPE_AGENT);
}

// ---------------------------------------------------------------------------
// Kernel 1: transpose w_rec [j][h] -> wrecT [h][j]  (4 MB, one-time per call)
// ---------------------------------------------------------------------------
__global__ void transpose1024(const float* __restrict__ in, float* __restrict__ out) {
    __shared__ float tile[32][33];
    const int tx = threadIdx.x, ty = threadIdx.y;
    const int xg = blockIdx.x * 32 + tx;
    const int ybase = blockIdx.y * 32;
#pragma unroll
    for (int r = 0; r < 32; r += 8)
        tile[ty + r][tx] = in[(size_t)(ybase + ty + r) * H + xg];
    __syncthreads();
    const int x2 = blockIdx.y * 32 + tx;
    const int y2base = blockIdx.x * 32;
#pragma unroll
    for (int r = 0; r < 32; r += 8)
        out[(size_t)(y2base + ty + r) * H + x2] = tile[tx][ty + r];
}

// ---------------------------------------------------------------------------
// Fused kernel (R19 = R18 + register-double-buffered GEMM K-loop ONLY).
// ---------------------------------------------------------------------------
__global__ void fused_gemm_scan(const float* __restrict__ x,
                                const float* __restrict__ w,
                                float* __restrict__ io,
                                const float* __restrict__ wrecT) {
    // shared memory union: GEMM needs 2*BK*LDSS floats (16896 B), scan needs
    // list[2][4][256] + cnt[2][4] ints (8224 B).
    __shared__ __align__(16) char smem[2 * BK * LDSS * sizeof(float)];

    const int slot = blockIdx.x & 7;
    if (slot >= 2) {
        // ------------- persistent GEMM path (R7 FMA order, dbuf staging) --
        const int gp = blockIdx.x >> 3;              // group 0..63
        const int pb = gp * 6 + (slot - 2);          // persistent id 0..383
        float* cur = io;

        float (*As)[LDSS] = reinterpret_cast<float (*)[LDSS]>(smem);
        float (*Bs)[LDSS] = reinterpret_cast<float (*)[LDSS]>(smem + BK * LDSS * sizeof(float));

        const int tid = threadIdx.x;
        const int tx = tid & 15, ty = tid >> 4;
        const int tx4 = tx * 4, ty4 = ty * 4;
        const int ar = tid >> 2;
        const int akc = (tid & 3) * 4;

        for (int wi = pb; wi < NUM_ITEMS; wi += PERS_BLOCKS) {
            const int m0 = (wi >> 3) * BM;           // ascending timestep
            const int n0 = (wi & 7) * BN;

            float acc[8][8];
#pragma unroll
            for (int i = 0; i < 8; ++i)
#pragma unroll
                for (int j = 0; j < 8; ++j) acc[i][j] = 0.0f;

            // prologue: issue k0=0 loads
            float4 a0 = *reinterpret_cast<const float4*>(&x[(size_t)(m0 + ar) * NIN + akc]);
            float4 a1 = *reinterpret_cast<const float4*>(&x[(size_t)(m0 + ar + 64) * NIN + akc]);
            float4 b0 = *reinterpret_cast<const float4*>(&w[(size_t)(n0 + ar) * NIN + akc]);
            float4 b1 = *reinterpret_cast<const float4*>(&w[(size_t)(n0 + ar + 64) * NIN + akc]);

            for (int k0 = 0; k0 < NIN; k0 += BK) {
                __syncthreads();      // prior compute done reading LDS
                As[akc + 0][ar] = a0.x; As[akc + 1][ar] = a0.y; As[akc + 2][ar] = a0.z; As[akc + 3][ar] = a0.w;
                As[akc + 0][ar + 64] = a1.x; As[akc + 1][ar + 64] = a1.y; As[akc + 2][ar + 64] = a1.z; As[akc + 3][ar + 64] = a1.w;
                Bs[akc + 0][ar] = b0.x; Bs[akc + 1][ar] = b0.y; Bs[akc + 2][ar] = b0.z; Bs[akc + 3][ar] = b0.w;
                Bs[akc + 0][ar + 64] = b1.x; Bs[akc + 1][ar + 64] = b1.y; Bs[akc + 2][ar + 64] = b1.z; Bs[akc + 3][ar + 64] = b1.w;
                __syncthreads();

                // issue NEXT K-tile's loads before compute (latency hides
                // under the FMA block). Clamp k to 0 on last iter: uniform,
                // branch-free, always-valid address (harmless warm re-read).
                const int kn = (k0 + BK < NIN) ? (k0 + BK) : 0;
                a0 = *reinterpret_cast<const float4*>(&x[(size_t)(m0 + ar) * NIN + kn + akc]);
                a1 = *reinterpret_cast<const float4*>(&x[(size_t)(m0 + ar + 64) * NIN + kn + akc]);
                b0 = *reinterpret_cast<const float4*>(&w[(size_t)(n0 + ar) * NIN + kn + akc]);
                b1 = *reinterpret_cast<const float4*>(&w[(size_t)(n0 + ar + 64) * NIN + kn + akc]);

#pragma unroll
                for (int kk = 0; kk < BK; ++kk) {
                    const float4 av0 = *reinterpret_cast<const float4*>(&As[kk][ty4]);
                    const float4 av1 = *reinterpret_cast<const float4*>(&As[kk][ty4 + 64]);
                    const float4 bv0 = *reinterpret_cast<const float4*>(&Bs[kk][tx4]);
                    const float4 bv1 = *reinterpret_cast<const float4*>(&Bs[kk][tx4 + 64]);
                    const float ar_[8] = {av0.x, av0.y, av0.z, av0.w, av1.x, av1.y, av1.z, av1.w};
                    const float br_[8] = {bv0.x, bv0.y, bv0.z, bv0.w, bv1.x, bv1.y, bv1.z, bv1.w};
#pragma unroll
                    for (int i = 0; i < 8; ++i)
#pragma unroll
                        for (int j = 0; j < 8; ++j)
                            acc[i][j] = fmaf(ar_[i], br_[j], acc[i][j]);
                }
            }

            // epilogue: agent-scope scalar stores (R15/R17-verbatim, coherent)
#pragma unroll
            for (int gi = 0; gi < 2; ++gi)
#pragma unroll
                for (int ii = 0; ii < 4; ++ii) {
                    const int i = gi * 4 + ii;
                    const int row = m0 + ty4 + ii + gi * 64;
                    float* dst = &cur[(size_t)row * H + n0 + tx4];
                    st_agent(dst + 0,  acc[i][0]); st_agent(dst + 1,  acc[i][1]);
                    st_agent(dst + 2,  acc[i][2]); st_agent(dst + 3,  acc[i][3]);
                    st_agent(dst + 64, acc[i][4]); st_agent(dst + 65, acc[i][5]);
                    st_agent(dst + 66, acc[i][6]); st_agent(dst + 67, acc[i][7]);
                }
        }
        return;
    }

    // ----------------------------- scan path (R8-verbatim) ----------------
    if (blockIdx.x >= 256) return;                 // only first 32 groups
    const int b = (blockIdx.x >> 3) * 2 + slot;    // 0..63
    const int tid = threadIdx.x;
    const int wave = tid >> 6, lane = tid & 63;
    const int j0 = tid * 4;

    int (*list)[4][256] = reinterpret_cast<int (*)[4][256]>(smem);          // 8192 B
    int (*cnt)[4]       = reinterpret_cast<int (*)[4]>(smem + 8192);        // 32 B

    float sv0 = 0.f, sv1 = 0.f, sv2 = 0.f, sv3 = 0.f;
    float si0 = 0.f, si1 = 0.f, si2 = 0.f, si3 = 0.f;
    float sb0 = 1.f, sb1 = 1.f, sb2 = 1.f, sb3 = 1.f;
    float sz0 = 0.f, sz1 = 0.f, sz2 = 0.f, sz3 = 0.f;
    int p = 0;

    const float C_MEM = (float)(1e-3 * 100.0);
    const float C_SYN = (float)(1e-3 * 200.0);
    const float C_AD  = (float)(1e-3 * (1.0 / 800.0));
    const float BETA  = 1.8f;

    float* base = io + (size_t)b * H + j0;

    if (lane == 0) cnt[0][wave] = 0;
    asm volatile("s_waitcnt lgkmcnt(0)" ::: "memory");
    __builtin_amdgcn_s_barrier();

    f32x4 P0, P1, P2, P3, P4, P5, P6, P7;

// one prefetch register: 4 agent-scope scalar loads + sentinel check
#define LDP(REG, KK)                                                          \
      REG.x = ld_agent(pb_ + (size_t)(KK) * BH + 0);                          \
      REG.y = ld_agent(pb_ + (size_t)(KK) * BH + 1);                          \
      REG.z = ld_agent(pb_ + (size_t)(KK) * BH + 2);                          \
      REG.w = ld_agent(pb_ + (size_t)(KK) * BH + 3);                          \
      bad_ |= (unsigned)(__float_as_uint(REG.x) == SENTU);                    \
      bad_ |= (unsigned)(__float_as_uint(REG.y) == SENTU);                    \
      bad_ |= (unsigned)(__float_as_uint(REG.z) == SENTU);                    \
      bad_ |= (unsigned)(__float_as_uint(REG.w) == SENTU);

// spin (bounded) until the next 8 steps of cur are all produced by the GEMM
#define LOADP8_SPIN(PBASE)                                                    \
  { const float* pb_ = (PBASE);                                               \
    for (int tries_ = 0; tries_ < (1 << 14); ++tries_) {                      \
      unsigned bad_ = 0u;                                                     \
      LDP(P0, 0) LDP(P1, 1) LDP(P2, 2) LDP(P3, 3)                             \
      LDP(P4, 4) LDP(P5, 5) LDP(P6, 6) LDP(P7, 7)                             \
      if (__ballot(bad_ != 0u) == 0ull) break;                                \
      __builtin_amdgcn_s_sleep(8);                                            \
    } }

    // chunk prefetch: 8 steps of cur (spin until GEMM has produced them)
    LOADP8_SPIN(base);

#define SCAN_STEP(T, CREG, PF)                                                \
  {                                                                           \
    const float cc0 = CREG.x, cc1 = CREG.y, cc2 = CREG.z, cc3 = CREG.w;       \
    const int4 cn = *reinterpret_cast<const int4*>(&cnt[p][0]);               \
    float r0 = 0.f, r1 = 0.f, r2 = 0.f, r3 = 0.f;                             \
    _Pragma("unroll")                                                         \
    for (int w = 0; w < 4; ++w) {                                             \
      const int nw = (w == 0) ? cn.x : (w == 1) ? cn.y : (w == 2) ? cn.z : cn.w; \
      const int* lst = &list[p][w][0];                                        \
      int a = 0;                                                              \
      for (; a + 8 <= nw; a += 8) {                                           \
        const int h0 = lst[a],     h1 = lst[a + 1];                           \
        const int h2 = lst[a + 2], h3 = lst[a + 3];                           \
        const int h4 = lst[a + 4], h5 = lst[a + 5];                           \
        const int h6 = lst[a + 6], h7 = lst[a + 7];                           \
        const f32x4 wa = *(const f32x4*)(wrecT + (size_t)h0 * H + j0);        \
        const f32x4 wb = *(const f32x4*)(wrecT + (size_t)h1 * H + j0);        \
        const f32x4 wc = *(const f32x4*)(wrecT + (size_t)h2 * H + j0);        \
        const f32x4 wd = *(const f32x4*)(wrecT + (size_t)h3 * H + j0);        \
        const f32x4 we = *(const f32x4*)(wrecT + (size_t)h4 * H + j0);        \
        const f32x4 wf = *(const f32x4*)(wrecT + (size_t)h5 * H + j0);        \
        const f32x4 wg = *(const f32x4*)(wrecT + (size_t)h6 * H + j0);        \
        const f32x4 wh = *(const f32x4*)(wrecT + (size_t)h7 * H + j0);        \
        r0 += wa.x; r1 += wa.y; r2 += wa.z; r3 += wa.w;                       \
        r0 += wb.x; r1 += wb.y; r2 += wb.z; r3 += wb.w;                       \
        r0 += wc.x; r1 += wc.y; r2 += wc.z; r3 += wc.w;                       \
        r0 += wd.x; r1 += wd.y; r2 += wd.z; r3 += wd.w;                       \
        r0 += we.x; r1 += we.y; r2 += we.z; r3 += we.w;                       \
        r0 += wf.x; r1 += wf.y; r2 += wf.z; r3 += wf.w;                       \
        r0 += wg.x; r1 += wg.y; r2 += wg.z; r3 += wg.w;                       \
        r0 += wh.x; r1 += wh.y; r2 += wh.z; r3 += wh.w;                       \
      }                                                                       \
      for (; a < nw; ++a) {                                                   \
        const int h = lst[a];                                                 \
        const f32x4 w4 = *(const f32x4*)(wrecT + (size_t)h * H + j0);         \
        r0 += w4.x; r1 += w4.y; r2 += w4.z; r3 += w4.w;                       \
      }                                                                       \
    }                                                                         \
    const float vd0 = sv0 + C_MEM * (0.0f - sv0 + si0);                       \
    const float vd1 = sv1 + C_MEM * (0.0f - sv1 + si1);                       \
    const float vd2 = sv2 + C_MEM * (0.0f - sv2 + si2);                       \
    const float vd3 = sv3 + C_MEM * (0.0f - sv3 + si3);                       \
    const float id0 = si0 - C_SYN * si0;                                      \
    const float id1 = si1 - C_SYN * si1;                                      \
    const float id2 = si2 - C_SYN * si2;                                      \
    const float id3 = si3 - C_SYN * si3;                                      \
    const float bd0 = sb0 + C_AD * (1.0f - sb0);                              \
    const float bd1 = sb1 + C_AD * (1.0f - sb1);                              \
    const float bd2 = sb2 + C_AD * (1.0f - sb2);                              \
    const float bd3 = sb3 + C_AD * (1.0f - sb3);                              \
    sz0 = ((vd0 - bd0) > 0.0f) ? 1.0f : 0.0f;                                 \
    sz1 = ((vd1 - bd1) > 0.0f) ? 1.0f : 0.0f;                                 \
    sz2 = ((vd2 - bd2) > 0.0f) ? 1.0f : 0.0f;                                 \
    sz3 = ((vd3 - bd3) > 0.0f) ? 1.0f : 0.0f;                                 \
    sv0 = (sz0 > 0.0f) ? 0.0f : vd0;                                          \
    sv1 = (sz1 > 0.0f) ? 0.0f : vd1;                                          \
    sv2 = (sz2 > 0.0f) ? 0.0f : vd2;                                          \
    sv3 = (sz3 > 0.0f) ? 0.0f : vd3;                                          \
    sb0 = (sz0 > 0.0f) ? (bd0 + BETA) : bd0;                                  \
    sb1 = (sz1 > 0.0f) ? (bd1 + BETA) : bd1;                                  \
    sb2 = (sz2 > 0.0f) ? (bd2 + BETA) : bd2;                                  \
    sb3 = (sz3 > 0.0f) ? (bd3 + BETA) : bd3;                                  \
    si0 = (id0 + cc0) + r0;                                                   \
    si1 = (id1 + cc1) + r1;                                                   \
    si2 = (id2 + cc2) + r2;                                                   \
    si3 = (id3 + cc3) + r3;                                                   \
    if (PF) {                                                                 \
      /* next chunk's cur loads (spin until produced by GEMM) */              \
      if ((T) + 1 < T_STEPS) {                                                \
        LOADP8_SPIN(base + (size_t)((T) + 1) * BH);                           \
      }                                                                       \
    }                                                                         \
    *reinterpret_cast<f32x4*>(base + (size_t)(T) * BH) =                      \
        (f32x4){sz0, sz1, sz2, sz3};                                          \
    const unsigned long long m0 = __ballot(sz0 > 0.0f);                       \
    const unsigned long long m1 = __ballot(sz1 > 0.0f);                       \
    const unsigned long long m2 = __ballot(sz2 > 0.0f);                       \
    const unsigned long long m3 = __ballot(sz3 > 0.0f);                       \
    unsigned pos = __builtin_amdgcn_mbcnt_hi((unsigned)(m0 >> 32),            \
                   __builtin_amdgcn_mbcnt_lo((unsigned)m0, 0u));              \
    pos = __builtin_amdgcn_mbcnt_hi((unsigned)(m1 >> 32),                     \
          __builtin_amdgcn_mbcnt_lo((unsigned)m1, pos));                      \
    pos = __builtin_amdgcn_mbcnt_hi((unsigned)(m2 >> 32),                     \
          __builtin_amdgcn_mbcnt_lo((unsigned)m2, pos));                      \
    pos = __builtin_amdgcn_mbcnt_hi((unsigned)(m3 >> 32),                     \
          __builtin_amdgcn_mbcnt_lo((unsigned)m3, pos));                      \
    int* dst = &list[p ^ 1][wave][0];                                         \
    if (sz0 > 0.0f) dst[pos++] = j0 + 0;                                      \
    if (sz1 > 0.0f) dst[pos++] = j0 + 1;                                      \
    if (sz2 > 0.0f) dst[pos++] = j0 + 2;                                      \
    if (sz3 > 0.0f) dst[pos++] = j0 + 3;                                      \
    if (lane == 0)                                                            \
      cnt[p ^ 1][wave] = __popcll(m0) + __popcll(m1) + __popcll(m2) + __popcll(m3); \
    asm volatile("s_waitcnt lgkmcnt(0)" ::: "memory");                        \
    __builtin_amdgcn_s_barrier();                                             \
    p ^= 1;                                                                   \
  }

    for (int t = 0; t < T_STEPS; t += 8) {
        SCAN_STEP(t,     P0, 0);
        SCAN_STEP(t + 1, P1, 0);
        SCAN_STEP(t + 2, P2, 0);
        SCAN_STEP(t + 3, P3, 0);
        SCAN_STEP(t + 4, P4, 0);
        SCAN_STEP(t + 5, P5, 0);
        SCAN_STEP(t + 6, P6, 0);
        SCAN_STEP(t + 7, P7, 1);
    }
#undef SCAN_STEP
#undef LOADP8_SPIN
#undef LDP

    float* fo = io + (size_t)T_STEPS * BH + (size_t)b * H + j0;
    *reinterpret_cast<float4*>(fo)          = make_float4(sz0, sz1, sz2, sz3);
    *reinterpret_cast<float4*>(fo + BH)     = make_float4(sv0, sv1, sv2, sv3);
    *reinterpret_cast<float4*>(fo + 2 * BH) = make_float4(si0, si1, si2, si3);
    *reinterpret_cast<float4*>(fo + 3 * BH) = make_float4(sb0, sb1, sb2, sb3);
}

// ---------------------------------------------------------------------------
extern "C" void kernel_launch(void* const* d_in, const int* in_sizes, int n_in,
                              void* d_out, int out_size, void* d_ws, size_t ws_size,
                              hipStream_t stream) {
    const float* x     = (const float*)d_in[0];
    const float* w_in  = (const float*)d_in[1];
    const float* w_rec = (const float*)d_in[2];
    float* out   = (float*)d_out;
    float* wrecT = (float*)d_ws;

    // arm the sentinel over the cur/z region (first T*BH floats of io)
    hipMemsetAsync(out, 0x7F, (size_t)T_STEPS * BH * sizeof(float), stream);
    transpose1024<<<dim3(H / 32, H / 32), dim3(32, 8), 0, stream>>>(w_rec, wrecT);
    fused_gemm_scan<<<dim3(GRID_BLOCKS), 256, 0, stream>>>(x, w_in, out, wrecT);
}